// Round 7
// baseline (4083.167 us; speedup 1.0000x reference)
//
#include <hip/hip_runtime.h>
#include <cstdint>
#include <cstddef>

#define DIM    1024
#define NH     16
#define HD     64
#define CHUNK_ 16
#define SEQ    4096
#define BATCH  4
#define NROWS  (BATCH * SEQ)       // 16384
#define NCHUNK (SEQ / CHUNK_)      // 256
#define SEG    64
#define NSEG   (SEQ / SEG)         // 64

using bf16x8 = __attribute__((ext_vector_type(8))) short;
using f32x4  = __attribute__((ext_vector_type(4))) float;
typedef union { bf16x8 v; uint32_t u[4]; } B8;

#define MFMA16(a, b, c) __builtin_amdgcn_mfma_f32_16x16x32_bf16((a), (b), (c), 0, 0, 0)

__device__ __forceinline__ ushort f2bf(float f) {
    uint32_t u = __float_as_uint(f);
    u += 0x7FFFu + ((u >> 16) & 1u);      // RTNE
    return (ushort)(u >> 16);
}
__device__ __forceinline__ uint32_t pack2(float a, float b) {
    return (uint32_t)f2bf(a) | ((uint32_t)f2bf(b) << 16);
}
__device__ __forceinline__ float b2f(ushort u) {
    return __uint_as_float(((uint32_t)u) << 16);
}
__device__ __forceinline__ float dot4(const float4 a, const float4 b) {
    return a.x*b.x + a.y*b.y + a.z*b.z + a.w*b.w;
}
__device__ __forceinline__ float redmax16(float x) {
    x = fmaxf(x, __shfl_xor(x, 1)); x = fmaxf(x, __shfl_xor(x, 2));
    x = fmaxf(x, __shfl_xor(x, 4)); x = fmaxf(x, __shfl_xor(x, 8));
    return x;
}
__device__ __forceinline__ float redsum16(float x) {
    x += __shfl_xor(x, 1); x += __shfl_xor(x, 2);
    x += __shfl_xor(x, 4); x += __shfl_xor(x, 8);
    return x;
}

// single-wave "barrier": compiler-only fence (verified round 6)
#define SYNC() do { asm volatile("" ::: "memory");          \
                    __builtin_amdgcn_wave_barrier();        \
                    __builtin_amdgcn_sched_barrier(0); } while (0)

// ---------------------------------------------------------------------------
// fp32 -> bf16 converter
// ---------------------------------------------------------------------------
__global__ __launch_bounds__(256)
void f2b_kernel(const float* __restrict__ in, ushort* __restrict__ out, int n8)
{
    int i = blockIdx.x * 256 + threadIdx.x;
    const int stride = gridDim.x * 256;
    for (; i < n8; i += stride) {
        float4 a = *(const float4*)&in[(size_t)i * 8];
        float4 b = *(const float4*)&in[(size_t)i * 8 + 4];
        uint4 u;
        u.x = pack2(a.x, a.y); u.y = pack2(a.z, a.w);
        u.z = pack2(b.x, b.y); u.w = pack2(b.z, b.w);
        *(uint4*)&out[(size_t)i * 8] = u;
    }
}

// ---------------------------------------------------------------------------
// Fused projection GEMM (NT), bf16 in/out, XCD swizzle, tensor-split epilogue.
// C_t[m][n] = sum_k A[m*K+k]*B[(t*1024+n)*K+k]; 4 output tensors contiguous.
// grid (32,128); verified staging/frag pattern from round 6.
// ---------------------------------------------------------------------------
__global__ __launch_bounds__(256)
void gemm_nt_bf16o(const ushort* __restrict__ A, const ushort* __restrict__ B,
                   ushort* __restrict__ C, int K)
{
    __shared__ ushort As[128][64];
    __shared__ ushort Bs[128][64];

    const int nwg  = gridDim.x * gridDim.y;
    const int bid0 = blockIdx.y * gridDim.x + blockIdx.x;
    const int qq   = nwg >> 3;
    const int sbid = (bid0 & 7) * qq + (bid0 >> 3);   // nwg % 8 == 0: bijective
    const int bx   = sbid % gridDim.x, by = sbid / gridDim.x;

    const int tid  = threadIdx.x, wave = tid >> 6, lane = tid & 63;
    const int m0   = by * 128, n0g = bx * 128;
    ushort* Cb     = C + (size_t)(n0g >> 10) * NROWS * DIM;
    const int n0   = n0g & 1023;
    const int lo   = lane & 15, kg = lane >> 4;
    const int wm   = (wave >> 1) * 64, wn = (wave & 1) * 64;
    const int srow = tid >> 1, shalf = tid & 1;
    const int rs   = srow & 7;
    const int swz  = lo & 7;

    f32x4 acc[4][4];
#pragma unroll
    for (int i = 0; i < 4; ++i)
#pragma unroll
        for (int j = 0; j < 4; ++j) acc[i][j] = (f32x4){0.f, 0.f, 0.f, 0.f};

    const ushort* Ap = A + (size_t)(m0 + srow) * K + shalf * 32;
    const ushort* Bp = B + (size_t)(n0g + srow) * K + shalf * 32;

    for (int kt = 0; kt < K; kt += 64) {
        uint4 av[4], bv[4];
#pragma unroll
        for (int j = 0; j < 4; ++j) {
            av[j] = *(const uint4*)(Ap + kt + j * 8);
            bv[j] = *(const uint4*)(Bp + kt + j * 8);
        }
        __syncthreads();
#pragma unroll
        for (int j = 0; j < 4; ++j) {
            *(uint4*)&As[srow][((shalf * 4 + j) ^ rs) * 8] = av[j];
            *(uint4*)&Bs[srow][((shalf * 4 + j) ^ rs) * 8] = bv[j];
        }
        __syncthreads();

        bf16x8 af[2][4], bfr[2][4];
#pragma unroll
        for (int kk = 0; kk < 2; ++kk)
#pragma unroll
            for (int m = 0; m < 4; ++m) {
                const int s = (kk * 4 + kg) ^ swz;
                af[kk][m]  = *(const bf16x8*)&As[wm + m * 16 + lo][s * 8];
                bfr[kk][m] = *(const bf16x8*)&Bs[wn + m * 16 + lo][s * 8];
            }
#pragma unroll
        for (int kk = 0; kk < 2; ++kk)
#pragma unroll
            for (int mt = 0; mt < 4; ++mt)
#pragma unroll
                for (int nt = 0; nt < 4; ++nt)
                    acc[mt][nt] = MFMA16(af[kk][mt], bfr[kk][nt], acc[mt][nt]);
    }

    const int col = lane & 15, r4 = (lane >> 4) * 4;
#pragma unroll
    for (int mt = 0; mt < 4; ++mt)
#pragma unroll
        for (int nt = 0; nt < 4; ++nt)
#pragma unroll
            for (int j = 0; j < 4; ++j)
                Cb[(size_t)(m0 + wm + mt * 16 + r4 + j) * DIM +
                   n0 + wn + nt * 16 + col] = f2bf(acc[mt][nt][j]);
}

// ---------------------------------------------------------------------------
// Final GEMM (NT), bf16 in, fp32 out, XCD swizzle. grid (8,128).
// ---------------------------------------------------------------------------
__global__ __launch_bounds__(256)
void gemm_nt_f32o(const ushort* __restrict__ A, const ushort* __restrict__ B,
                  float* __restrict__ C, int K)
{
    __shared__ ushort As[128][64];
    __shared__ ushort Bs[128][64];

    const int nwg  = gridDim.x * gridDim.y;
    const int bid0 = blockIdx.y * gridDim.x + blockIdx.x;
    const int qq   = nwg >> 3;
    const int sbid = (bid0 & 7) * qq + (bid0 >> 3);
    const int bx   = sbid % gridDim.x, by = sbid / gridDim.x;

    const int tid  = threadIdx.x, wave = tid >> 6, lane = tid & 63;
    const int m0   = by * 128, n0 = bx * 128;
    const int lo   = lane & 15, kg = lane >> 4;
    const int wm   = (wave >> 1) * 64, wn = (wave & 1) * 64;
    const int srow = tid >> 1, shalf = tid & 1;
    const int rs   = srow & 7;
    const int swz  = lo & 7;

    f32x4 acc[4][4];
#pragma unroll
    for (int i = 0; i < 4; ++i)
#pragma unroll
        for (int j = 0; j < 4; ++j) acc[i][j] = (f32x4){0.f, 0.f, 0.f, 0.f};

    const ushort* Ap = A + (size_t)(m0 + srow) * K + shalf * 32;
    const ushort* Bp = B + (size_t)(n0 + srow) * K + shalf * 32;

    for (int kt = 0; kt < K; kt += 64) {
        uint4 av[4], bv[4];
#pragma unroll
        for (int j = 0; j < 4; ++j) {
            av[j] = *(const uint4*)(Ap + kt + j * 8);
            bv[j] = *(const uint4*)(Bp + kt + j * 8);
        }
        __syncthreads();
#pragma unroll
        for (int j = 0; j < 4; ++j) {
            *(uint4*)&As[srow][((shalf * 4 + j) ^ rs) * 8] = av[j];
            *(uint4*)&Bs[srow][((shalf * 4 + j) ^ rs) * 8] = bv[j];
        }
        __syncthreads();

        bf16x8 af[2][4], bfr[2][4];
#pragma unroll
        for (int kk = 0; kk < 2; ++kk)
#pragma unroll
            for (int m = 0; m < 4; ++m) {
                const int s = (kk * 4 + kg) ^ swz;
                af[kk][m]  = *(const bf16x8*)&As[wm + m * 16 + lo][s * 8];
                bfr[kk][m] = *(const bf16x8*)&Bs[wn + m * 16 + lo][s * 8];
            }
#pragma unroll
        for (int kk = 0; kk < 2; ++kk)
#pragma unroll
            for (int mt = 0; mt < 4; ++mt)
#pragma unroll
                for (int nt = 0; nt < 4; ++nt)
                    acc[mt][nt] = MFMA16(af[kk][mt], bfr[kk][nt], acc[mt][nt]);
    }

    const int col = lane & 15, r4 = (lane >> 4) * 4;
#pragma unroll
    for (int mt = 0; mt < 4; ++mt)
#pragma unroll
        for (int nt = 0; nt < 4; ++nt)
#pragma unroll
            for (int j = 0; j < 4; ++j)
                C[(size_t)(m0 + wm + mt * 16 + r4 + j) * DIM +
                  n0 + wn + nt * 16 + col] = acc[mt][nt][j];
}

// ---------------------------------------------------------------------------
// lr kernel (exact fp32)
// ---------------------------------------------------------------------------
__global__ __launch_bounds__(256)
void lr_kernel(const float* __restrict__ hs, const float* __restrict__ Wlr,
               float* __restrict__ LR)
{
    __shared__ float row[DIM];
    const int r = blockIdx.x;
    const int t = threadIdx.x;
    *(float4*)&row[t * 4] = *(const float4*)&hs[(size_t)r * DIM + t * 4];
    __syncthreads();

    const int o = t >> 3;
    const int p = t & 7;
    const float* w = Wlr + (size_t)o * DIM + p * 128;
    const float* x = row + p * 128;
    float acc = 0.f;
#pragma unroll
    for (int i = 0; i < 32; ++i) {
        float4 xv = *(const float4*)(x + i * 4);
        float4 wv = *(const float4*)(w + i * 4);
        acc += dot4(xv, wv);
    }
    acc += __shfl_xor(acc, 1);
    acc += __shfl_xor(acc, 2);
    acc += __shfl_xor(acc, 4);
    if (p == 0) {
        float xx = acc + 0.001f;
        LR[(size_t)r * 32 + o] = (xx > 20.f) ? xx : log1pf(expf(xx));
    }
}

// ---------------------------------------------------------------------------
// halo save (bf16 buffers)
// ---------------------------------------------------------------------------
__global__ __launch_bounds__(256)
void halo_save(const ushort* __restrict__ Q, const ushort* __restrict__ K,
               const ushort* __restrict__ V, ushort* __restrict__ HALO)
{
    int idx = blockIdx.x;
    int tn  = idx / (BATCH * (NSEG - 1) * 3);
    int rem = idx - tn * (BATCH * (NSEG - 1) * 3);
    int b   = rem / ((NSEG - 1) * 3);
    int rem2= rem - b * ((NSEG - 1) * 3);
    int s   = rem2 / 3 + 1;
    int j   = rem2 - (s - 1) * 3;

    const ushort* buf = (tn == 0) ? Q : ((tn == 1) ? K : V);
    size_t src = ((size_t)(b * SEQ + s * SEG - 3 + j)) * DIM + threadIdx.x * 4;
    size_t dst = ((size_t)((tn * BATCH + b) * NSEG + s) * 3 + j) * DIM + threadIdx.x * 4;
    *(uint2*)&HALO[dst] = *(const uint2*)&buf[src];
}

// ---------------------------------------------------------------------------
// conv in-place (bf16 buffers, fp32 math)
// ---------------------------------------------------------------------------
__global__ __launch_bounds__(256)
void conv_inplace(ushort* __restrict__ Q, ushort* __restrict__ K,
                  ushort* __restrict__ V, const ushort* __restrict__ HALO,
                  const float* __restrict__ cq, const float* __restrict__ ck,
                  const float* __restrict__ cv)
{
    const int wid  = (blockIdx.x << 2) + (threadIdx.x >> 6);
    const int lane = threadIdx.x & 63;
    const int tn   = wid >> 12;
    const int rem  = wid & 4095;
    const int b    = rem >> 10;
    const int rem2 = rem & 1023;
    const int h    = rem2 >> 6;
    const int s    = rem2 & 63;
    const int c    = (h << 6) + lane;

    ushort* buf = (tn == 0) ? Q : ((tn == 1) ? K : V);
    const float* cw = (tn == 0) ? cq : ((tn == 1) ? ck : cv);
    float4 w4 = *(const float4*)(cw + (c << 2));

    float xm3 = 0.f, xm2 = 0.f, xm1 = 0.f;
    if (s > 0) {
        size_t hb = ((size_t)((tn * BATCH + b) * NSEG + s) * 3) * DIM + c;
        xm3 = b2f(HALO[hb]);
        xm2 = b2f(HALO[hb + DIM]);
        xm1 = b2f(HALO[hb + 2 * DIM]);
    }

    size_t base = ((size_t)(b * SEQ + s * SEG)) * DIM + c;
    float x_next = b2f(buf[base]);
#pragma unroll 4
    for (int i = 0; i < SEG; ++i) {
        float x = x_next;
        if (i < SEG - 1) x_next = b2f(buf[base + (size_t)(i + 1) * DIM]);
        float y = xm3 * w4.x + xm2 * w4.y + xm1 * w4.z + x * w4.w + x;
        y = y / (1.f + __expf(-y));
        if (tn < 2) {
            float n2 = y * y;
#pragma unroll
            for (int m = 1; m < 64; m <<= 1) n2 += __shfl_xor(n2, m);
            y *= rsqrtf(n2);
        }
        buf[base + (size_t)i * DIM] = f2bf(y);
        xm3 = xm2; xm2 = xm1; xm1 = x;
    }
}

// ---------------------------------------------------------------------------
// Dual-chain MFMA scan: ONE WAVE per TWO (b,h) chains (bid, bid+32).
// Per-chain math identical to verified round-6 kernel; phases duplicated
// A;B inside each fence-free region so the scheduler interleaves the two
// independent dependency chains.
// ---------------------------------------------------------------------------
struct Ch {
    ushort (*QA)[72]; ushort (*KA)[72]; ushort (*VA)[72]; ushort (*sG)[72];
    ushort (*KT)[24]; ushort (*VT)[40];
    ushort (*WiA)[72]; ushort (*WoA)[72];
    ushort (*QKT)[32]; ushort (*P0s)[32]; ushort (*P1s)[32]; ushort (*KH)[32];
    const ushort *QP, *KP, *VP, *GP;
    const float *LRp;
    ushort *OBp;
    int rowb, lrbase;
    uint2 pq[4], pk[4], pv[4], pg[4];
    float plr;
    f32x4 wiC[4], woC[4];
    f32x4 cK;
    float lr1, lr_in, lr_out;
};

__device__ __forceinline__ void ch_prefetch(Ch& c, int rb) {
    const int t = threadIdx.x, lo = t & 15, g = t >> 4;
#pragma unroll
    for (int i = 0; i < 4; ++i) {
        size_t go = (size_t)(rb + i * 4 + g) * DIM + 4 * lo;
        c.pq[i] = *(const uint2*)&c.QP[go];
        c.pk[i] = *(const uint2*)&c.KP[go];
        c.pv[i] = *(const uint2*)&c.VP[go];
        c.pg[i] = *(const uint2*)&c.GP[go];
    }
    const int tt = t - c.lrbase;
    if ((unsigned)tt < 32u)
        c.plr = c.LRp[(size_t)(rb + (tt >> 1)) * 32 + (tt & 1)];
}

__device__ __forceinline__ void ch_stage(Ch& c) {
    const int t = threadIdx.x, lo = t & 15, g = t >> 4;
#pragma unroll
    for (int i = 0; i < 4; ++i) {
        const int row = i * 4 + g;
        *(uint2*)&c.QA[row][4 * lo] = c.pq[i];
        *(uint2*)&c.KA[row][4 * lo] = c.pk[i];
        *(uint2*)&c.VA[row][4 * lo] = c.pv[i];
        *(uint2*)&c.sG[row][4 * lo] = c.pg[i];
        uint2 uk = c.pk[i], uv = c.pv[i];
        c.KT[4 * lo + 0][row] = (ushort)(uk.x & 0xFFFF);
        c.KT[4 * lo + 1][row] = (ushort)(uk.x >> 16);
        c.KT[4 * lo + 2][row] = (ushort)(uk.y & 0xFFFF);
        c.KT[4 * lo + 3][row] = (ushort)(uk.y >> 16);
        c.VT[4 * lo + 0][row] = (ushort)(uv.x & 0xFFFF);
        c.VT[4 * lo + 1][row] = (ushort)(uv.x >> 16);
        c.VT[4 * lo + 2][row] = (ushort)(uv.y & 0xFFFF);
        c.VT[4 * lo + 3][row] = (ushort)(uv.y >> 16);
    }
    c.lr1    = __shfl(c.plr, c.lrbase + 2 * lo + 1);
    c.lr_in  = __shfl(c.plr, c.lrbase + 0);
    c.lr_out = __shfl(c.plr, c.lrbase + 1);
}

__device__ __forceinline__ void ch_qk(Ch& c) {
    const int t = threadIdx.x, lo = t & 15, g = t >> 4;
    const f32x4 z4 = (f32x4){0.f, 0.f, 0.f, 0.f};
    bf16x8 xWi0 = *(const bf16x8*)&c.WiA[lo][g * 8];
    bf16x8 xWi1 = *(const bf16x8*)&c.WiA[lo][g * 8 + 32];
    f32x4 cK = MFMA16(xWi0, *(const bf16x8*)&c.KA[lo][g * 8], z4);
    cK = MFMA16(xWi1, *(const bf16x8*)&c.KA[lo][g * 8 + 32], cK);
    f32x4 cQ = MFMA16(xWi0, *(const bf16x8*)&c.QA[lo][g * 8], z4);
    cQ = MFMA16(xWi1, *(const bf16x8*)&c.QA[lo][g * 8 + 32], cQ);
    c.cK = cK;

    float mK = fmaxf(fmaxf(cK[0], cK[1]), fmaxf(cK[2], cK[3]));
    float ek0 = __expf(cK[0] - mK), ek1 = __expf(cK[1] - mK);
    float ek2 = __expf(cK[2] - mK), ek3 = __expf(cK[3] - mK);
    float ivk = c.lr1 / (ek0 + ek1 + ek2 + ek3);
    float kh0 = ek0 * ivk, kh1 = ek1 * ivk, kh2 = ek2 * ivk, kh3 = ek3 * ivk;

    float mQ = fmaxf(fmaxf(cQ[0], cQ[1]), fmaxf(cQ[2], cQ[3]));
    float eq0 = __expf(cQ[0] - mQ), eq1 = __expf(cQ[1] - mQ);
    float eq2 = __expf(cQ[2] - mQ), eq3 = __expf(cQ[3] - mQ);
    float ivq = 1.f / (eq0 + eq1 + eq2 + eq3);
    float qh0 = eq0 * ivq, qh1 = eq1 * ivq, qh2 = eq2 * ivq, qh3 = eq3 * ivq;

    B8 aQh, bKh;
    aQh.u[0] = aQh.u[1] = aQh.u[2] = aQh.u[3] = 0;
    bKh.u[0] = bKh.u[1] = bKh.u[2] = bKh.u[3] = 0;
    if (g == 0) {
        aQh.u[0] = pack2(qh0, qh1); aQh.u[1] = pack2(qh2, qh3);
        bKh.u[0] = pack2(kh0, kh1); bKh.u[1] = pack2(kh2, kh3);
    }
    f32x4 cQK = MFMA16(aQh.v, bKh.v, z4);
#pragma unroll
    for (int r = 0; r < 4; ++r) {
        const int q = 4 * g + r;
        c.QKT[q][lo] = (lo <= q) ? f2bf(cQK[r]) : (ushort)0;
    }
    if (g == 0) {
        c.QKT[lo][16] = f2bf(qh0); c.QKT[lo][17] = f2bf(qh1);
        c.QKT[lo][18] = f2bf(qh2); c.QKT[lo][19] = f2bf(qh3);
        c.KH[0][lo] = f2bf(kh0); c.KH[1][lo] = f2bf(kh1);
        c.KH[2][lo] = f2bf(kh2); c.KH[3][lo] = f2bf(kh3);
    }
}

__device__ __forceinline__ void ch_out_upd1(Ch& c, int rb,
                                            const float* lnGr, const float* lnBr) {
    const int t = threadIdx.x, lo = t & 15, g = t >> 4;
    const f32x4 z4 = (f32x4){0.f, 0.f, 0.f, 0.f};
    bf16x8 aO = *(const bf16x8*)&c.QKT[lo][g * 8];
    f32x4 oA[4];
#pragma unroll
    for (int n = 0; n < 4; ++n)
        oA[n] = MFMA16(aO, *(const bf16x8*)&c.VT[16 * n + lo][g * 8], z4);
#pragma unroll
    for (int r = 0; r < 4; ++r) {
        float s1 = oA[0][r] + oA[1][r] + oA[2][r] + oA[3][r];
        float s2 = oA[0][r] * oA[0][r] + oA[1][r] * oA[1][r] +
                   oA[2][r] * oA[2][r] + oA[3][r] * oA[3][r];
        s1 = redsum16(s1); s2 = redsum16(s2);
        float mu = s1 * (1.f / 64.f);
        float rstd = rsqrtf(s2 * (1.f / 64.f) - mu * mu + 1e-5f);
        const int q = 4 * g + r;
#pragma unroll
        for (int n = 0; n < 4; ++n) {
            float val = (oA[n][r] - mu) * rstd * lnGr[n] + lnBr[n];
            val *= b2f(c.sG[q][16 * n + lo]);
            c.OBp[(size_t)(rb + q) * DIM + 16 * n + lo] = f2bf(val);
        }
    }
    bf16x8 aKH = *(const bf16x8*)&c.KH[lo][g * 8];
#pragma unroll
    for (int n = 0; n < 4; ++n)
        c.woC[n] = MFMA16(aKH, *(const bf16x8*)&c.VT[16 * n + lo][g * 8], c.woC[n]);
    if (g == 0) {
#pragma unroll
        for (int n = 0; n < 4; ++n)
#pragma unroll
            for (int D = 0; D < 4; ++D)
                c.WoA[D][16 * n + lo] = f2bf(c.woC[n][D]);
    }
}

template<int IT>
__device__ __forceinline__ void ch_inner_scores(Ch& c) {
    const int t = threadIdx.x, lo = t & 15, g = t >> 4;
    const f32x4 z4 = (f32x4){0.f, 0.f, 0.f, 0.f};
    f32x4 s0v;
    if (IT == 0) {
        s0v = c.cK;                       // Wi unchanged since logits
    } else {
        bf16x8 y0 = *(const bf16x8*)&c.WiA[lo][g * 8];
        bf16x8 y1 = *(const bf16x8*)&c.WiA[lo][g * 8 + 32];
        s0v = MFMA16(y0, *(const bf16x8*)&c.KA[lo][g * 8], z4);
        s0v = MFMA16(y1, *(const bf16x8*)&c.KA[lo][g * 8 + 32], s0v);
    }
    bf16x8 w0 = *(const bf16x8*)&c.WoA[lo][g * 8];
    bf16x8 w1 = *(const bf16x8*)&c.WoA[lo][g * 8 + 32];
    f32x4 s1v = MFMA16(w0, *(const bf16x8*)&c.VA[lo][g * 8], z4);
    s1v = MFMA16(w1, *(const bf16x8*)&c.VA[lo][g * 8 + 32], s1v);

    float p0v[4], p1v[4];
#pragma unroll
    for (int r = 0; r < 4; ++r) {
        float x0 = s0v[r] * 0.125f, x1 = s1v[r] * 0.125f;
        float m0v = redmax16(x0), m1v = redmax16(x1);
        float e0 = __expf(x0 - m0v), e1 = __expf(x1 - m1v);
        p0v[r] = e0 / redsum16(e0);
        p1v[r] = e1 / redsum16(e1);
    }
    if (g == 0) {
#pragma unroll
        for (int r = 0; r < 4; ++r) {
            c.P0s[r][lo] = f2bf(p0v[r] * c.lr_out);
            c.P1s[r][lo] = f2bf(p1v[r] * c.lr_in);
        }
    }
}

__device__ __forceinline__ void ch_inner_upd(Ch& c, bool last) {
    const int t = threadIdx.x, lo = t & 15, g = t >> 4;
    bf16x8 aP0 = *(const bf16x8*)&c.P0s[lo][g * 8];
    bf16x8 aP1 = *(const bf16x8*)&c.P1s[lo][g * 8];
#pragma unroll
    for (int n = 0; n < 4; ++n) {
        c.woC[n] = MFMA16(aP0, *(const bf16x8*)&c.VT[16 * n + lo][g * 8], c.woC[n]);
        c.wiC[n] = MFMA16(aP1, *(const bf16x8*)&c.KT[16 * n + lo][g * 8], c.wiC[n]);
    }
    if (g == 0) {
#pragma unroll
        for (int n = 0; n < 4; ++n)
#pragma unroll
            for (int D = 0; D < 4; ++D) {
                c.WiA[D][16 * n + lo] = f2bf(c.wiC[n][D]);
                c.WoA[D][16 * n + lo] = f2bf(c.woC[n][D]);
                if (last) c.VT[16 * n + lo][16 + D] = f2bf(c.woC[n][D]);
            }
    }
}

__global__ __launch_bounds__(64)
void scan_kernel(const ushort* QP, const ushort* KP, const ushort* VP,
                 const float* LRb, const ushort* GP,
                 const float* Wi0, const float* Wo0,
                 const float* lng, const float* lnb, ushort* OB)
{
    __shared__ ushort QA2[2][16][72], KA2[2][16][72], VA2[2][16][72], sG2[2][16][72];
    __shared__ ushort KT2[2][64][24], VT2[2][64][40];
    __shared__ ushort WiA2[2][16][72], WoA2[2][16][72];
    __shared__ ushort QKT2[2][16][32], P0s2[2][16][32], P1s2[2][16][32], KH2[2][16][32];

    const int t = threadIdx.x, lo = t & 15, g = t >> 4;

    for (int i = t; i < 2 * 16 * 72; i += 64) {
        ((ushort*)QA2)[i] = 0; ((ushort*)KA2)[i] = 0; ((ushort*)VA2)[i] = 0;
        ((ushort*)sG2)[i] = 0; ((ushort*)WiA2)[i] = 0; ((ushort*)WoA2)[i] = 0;
    }
    for (int i = t; i < 2 * 64 * 24; i += 64) ((ushort*)KT2)[i] = 0;
    for (int i = t; i < 2 * 64 * 40; i += 64) ((ushort*)VT2)[i] = 0;
    for (int i = t; i < 2 * 16 * 32; i += 64) {
        ((ushort*)QKT2)[i] = 0; ((ushort*)P0s2)[i] = 0;
        ((ushort*)P1s2)[i] = 0; ((ushort*)KH2)[i] = 0;
    }

    Ch CA, CB;
    auto setup = [&](Ch& c, int chain, int idx) {
        const int b = chain >> 4, h = chain & 15;
        c.QA = QA2[idx]; c.KA = KA2[idx]; c.VA = VA2[idx]; c.sG = sG2[idx];
        c.KT = KT2[idx]; c.VT = VT2[idx];
        c.WiA = WiA2[idx]; c.WoA = WoA2[idx];
        c.QKT = QKT2[idx]; c.P0s = P0s2[idx]; c.P1s = P1s2[idx]; c.KH = KH2[idx];
        c.QP = QP + h * 64; c.KP = KP + h * 64; c.VP = VP + h * 64; c.GP = GP + h * 64;
        c.LRp = LRb + h * 2;
        c.OBp = OB + h * 64;
        c.rowb = b * SEQ;
        c.lrbase = idx * 32;
        c.plr = 0.f;
#pragma unroll
        for (int n = 0; n < 4; ++n) {
            c.wiC[n] = (f32x4){0.f, 0.f, 0.f, 0.f};
            c.woC[n] = (f32x4){0.f, 0.f, 0.f, 0.f};
        }
        if (g == 0) {
#pragma unroll
            for (int n = 0; n < 4; ++n)
#pragma unroll
                for (int D = 0; D < 4; ++D) {
                    float wi = Wi0[((size_t)D * NH + h) * HD + 16 * n + lo];
                    float wo = Wo0[((size_t)D * NH + h) * HD + 16 * n + lo];
                    c.wiC[n][D] = wi; c.woC[n][D] = wo;
                    c.WiA[D][16 * n + lo] = f2bf(wi);
                    c.WoA[D][16 * n + lo] = f2bf(wo);
                    c.VT[16 * n + lo][16 + D] = f2bf(wo);
                }
        }
    };
    setup(CA, blockIdx.x, 0);
    setup(CB, blockIdx.x + 32, 1);

    float lnGr[4], lnBr[4];
#pragma unroll
    for (int n = 0; n < 4; ++n) { lnGr[n] = lng[16 * n + lo]; lnBr[n] = lnb[16 * n + lo]; }

    ch_prefetch(CA, CA.rowb);
    ch_prefetch(CB, CB.rowb);
    SYNC();

    for (int cc = 0; cc < NCHUNK; ++cc) {
        const int rbA = CA.rowb + cc * CHUNK_;
        const int rbB = CB.rowb + cc * CHUNK_;

        ch_stage(CA); ch_stage(CB);
        if (cc + 1 < NCHUNK) {
            ch_prefetch(CA, rbA + CHUNK_);
            ch_prefetch(CB, rbB + CHUNK_);
        }
        SYNC();

        ch_qk(CA); ch_qk(CB);
        SYNC();

        ch_out_upd1(CA, rbA, lnGr, lnBr); ch_out_upd1(CB, rbB, lnGr, lnBr);
        SYNC();

        ch_inner_scores<0>(CA); ch_inner_scores<0>(CB);
        SYNC();
        ch_inner_upd(CA, false); ch_inner_upd(CB, false);
        SYNC();
        ch_inner_scores<1>(CA); ch_inner_scores<1>(CB);
        SYNC();
        ch_inner_upd(CA, true); ch_inner_upd(CB, true);
        SYNC();
    }
}

// ---------------------------------------------------------------------------
// launch
// ---------------------------------------------------------------------------
extern "C" void kernel_launch(void* const* d_in, const int* in_sizes, int n_in,
                              void* d_out, int out_size, void* d_ws, size_t ws_size,
                              hipStream_t stream)
{
    const float* hs  = (const float*)d_in[0];
    const float* Wq  = (const float*)d_in[1];
    const float* Wk  = (const float*)d_in[2];
    const float* Wv  = (const float*)d_in[3];
    const float* Wlr = (const float*)d_in[4];
    const float* Wg  = (const float*)d_in[5];
    const float* Wo  = (const float*)d_in[6];
    const float* cq  = (const float*)d_in[7];
    const float* ck  = (const float*)d_in[8];
    const float* cv  = (const float*)d_in[9];
    const float* Wi0 = (const float*)d_in[10];
    const float* Wo0 = (const float*)d_in[11];
    const float* lng = (const float*)d_in[12];
    const float* lnb = (const float*)d_in[13];

    // ws (~177 MB): Qb|Kb|Vb|Gb bf16 (contiguous, fused-GEMM C) | hsb bf16
    // (->OBUF) | Wqb..Wgb,Wob bf16 (contiguous, fused-GEMM B) | HALO bf16 | LR f32
    ushort* Qb  = (ushort*)d_ws;
    ushort* Kb  = Qb + (size_t)NROWS * DIM;
    ushort* Vb  = Kb + (size_t)NROWS * DIM;
    ushort* Gb  = Vb + (size_t)NROWS * DIM;
    ushort* hsb = Gb + (size_t)NROWS * DIM;
    ushort* Wqb = hsb + (size_t)NROWS * DIM;
    ushort* Wkb = Wqb + (size_t)DIM * DIM;
    ushort* Wvb = Wkb + (size_t)DIM * DIM;
    ushort* Wgb = Wvb + (size_t)DIM * DIM;
    ushort* Wob = Wgb + (size_t)DIM * DIM;
    ushort* HALO = Wob + (size_t)DIM * DIM;
    float*  LRb  = (float*)(HALO + (size_t)3 * BATCH * NSEG * 3 * DIM);
    ushort* OBUF = hsb;   // hs bf16 dead after projections (stream-ordered)

    dim3 blk(256);

    f2b_kernel<<<2048, blk, 0, stream>>>(hs, hsb, NROWS * DIM / 8);
    f2b_kernel<<<512, blk, 0, stream>>>(Wq, Wqb, DIM * DIM / 8);
    f2b_kernel<<<512, blk, 0, stream>>>(Wk, Wkb, DIM * DIM / 8);
    f2b_kernel<<<512, blk, 0, stream>>>(Wv, Wvb, DIM * DIM / 8);
    f2b_kernel<<<512, blk, 0, stream>>>(Wg, Wgb, DIM * DIM / 8);
    f2b_kernel<<<512, blk, 0, stream>>>(Wo, Wob, DIM * DIM / 8);

    // fused q|k|v|gate projection: B = [Wqb;Wkb;Wvb;Wgb], C = [Qb;Kb;Vb;Gb]
    gemm_nt_bf16o<<<dim3(32, 128), blk, 0, stream>>>(hsb, Wqb, Qb, 1024);

    lr_kernel<<<NROWS, blk, 0, stream>>>(hs, Wlr, LRb);

    halo_save<<<3 * BATCH * (NSEG - 1) * 3, blk, 0, stream>>>(Qb, Kb, Vb, HALO);
    conv_inplace<<<(3 * BATCH * NH * NSEG) / 4, blk, 0, stream>>>(Qb, Kb, Vb, HALO,
                                                                  cq, ck, cv);

    scan_kernel<<<32, dim3(64), 0, stream>>>(Qb, Kb, Vb, LRb, Gb,
                                             Wi0, Wo0, lng, lnb, OBUF);

    gemm_nt_f32o<<<dim3(8, 128), blk, 0, stream>>>(OBUF, Wob, (float*)d_out, 1024);
}

// Round 8
// 3659.899 us; speedup vs baseline: 1.1157x; 1.1157x over previous
//
#include <hip/hip_runtime.h>
#include <cstdint>
#include <cstddef>

#define DIM    1024
#define NH     16
#define HD     64
#define CHUNK_ 16
#define SEQ    4096
#define BATCH  4
#define NROWS  (BATCH * SEQ)       // 16384
#define NCHUNK (SEQ / CHUNK_)      // 256
#define SEG    64
#define NSEG   (SEQ / SEG)         // 64

using bf16x8 = __attribute__((ext_vector_type(8))) short;
using f32x4  = __attribute__((ext_vector_type(4))) float;
typedef union { bf16x8 v; uint32_t u[4]; } B8;

#define MFMA16(a, b, c) __builtin_amdgcn_mfma_f32_16x16x32_bf16((a), (b), (c), 0, 0, 0)

__device__ __forceinline__ ushort f2bf(float f) {
    uint32_t u = __float_as_uint(f);
    u += 0x7FFFu + ((u >> 16) & 1u);      // RTNE
    return (ushort)(u >> 16);
}
__device__ __forceinline__ uint32_t pack2(float a, float b) {
    return (uint32_t)f2bf(a) | ((uint32_t)f2bf(b) << 16);
}
__device__ __forceinline__ float b2f(ushort u) {
    return __uint_as_float(((uint32_t)u) << 16);
}
__device__ __forceinline__ float dot4(const float4 a, const float4 b) {
    return a.x*b.x + a.y*b.y + a.z*b.z + a.w*b.w;
}
__device__ __forceinline__ float redmax16(float x) {
    x = fmaxf(x, __shfl_xor(x, 1)); x = fmaxf(x, __shfl_xor(x, 2));
    x = fmaxf(x, __shfl_xor(x, 4)); x = fmaxf(x, __shfl_xor(x, 8));
    return x;
}
__device__ __forceinline__ float redsum16(float x) {
    x += __shfl_xor(x, 1); x += __shfl_xor(x, 2);
    x += __shfl_xor(x, 4); x += __shfl_xor(x, 8);
    return x;
}

// intra-wave "barrier": compiler-only fence (verified round 6). Waves in the
// block are fully independent (own chain, own LDS slice) -> no s_barrier.
#define SYNC() do { asm volatile("" ::: "memory");          \
                    __builtin_amdgcn_wave_barrier();        \
                    __builtin_amdgcn_sched_barrier(0); } while (0)

// ---------------------------------------------------------------------------
// fp32 -> bf16 converter
// ---------------------------------------------------------------------------
__global__ __launch_bounds__(256)
void f2b_kernel(const float* __restrict__ in, ushort* __restrict__ out, int n8)
{
    int i = blockIdx.x * 256 + threadIdx.x;
    const int stride = gridDim.x * 256;
    for (; i < n8; i += stride) {
        float4 a = *(const float4*)&in[(size_t)i * 8];
        float4 b = *(const float4*)&in[(size_t)i * 8 + 4];
        uint4 u;
        u.x = pack2(a.x, a.y); u.y = pack2(a.z, a.w);
        u.z = pack2(b.x, b.y); u.w = pack2(b.z, b.w);
        *(uint4*)&out[(size_t)i * 8] = u;
    }
}

// ---------------------------------------------------------------------------
// Fused projection GEMM (NT), bf16 in/out (verified round 7)
// ---------------------------------------------------------------------------
__global__ __launch_bounds__(256)
void gemm_nt_bf16o(const ushort* __restrict__ A, const ushort* __restrict__ B,
                   ushort* __restrict__ C, int K)
{
    __shared__ ushort As[128][64];
    __shared__ ushort Bs[128][64];

    const int nwg  = gridDim.x * gridDim.y;
    const int bid0 = blockIdx.y * gridDim.x + blockIdx.x;
    const int qq   = nwg >> 3;
    const int sbid = (bid0 & 7) * qq + (bid0 >> 3);
    const int bx   = sbid % gridDim.x, by = sbid / gridDim.x;

    const int tid  = threadIdx.x, wave = tid >> 6, lane = tid & 63;
    const int m0   = by * 128, n0g = bx * 128;
    ushort* Cb     = C + (size_t)(n0g >> 10) * NROWS * DIM;
    const int n0   = n0g & 1023;
    const int lo   = lane & 15, kg = lane >> 4;
    const int wm   = (wave >> 1) * 64, wn = (wave & 1) * 64;
    const int srow = tid >> 1, shalf = tid & 1;
    const int rs   = srow & 7;
    const int swz  = lo & 7;

    f32x4 acc[4][4];
#pragma unroll
    for (int i = 0; i < 4; ++i)
#pragma unroll
        for (int j = 0; j < 4; ++j) acc[i][j] = (f32x4){0.f, 0.f, 0.f, 0.f};

    const ushort* Ap = A + (size_t)(m0 + srow) * K + shalf * 32;
    const ushort* Bp = B + (size_t)(n0g + srow) * K + shalf * 32;

    for (int kt = 0; kt < K; kt += 64) {
        uint4 av[4], bv[4];
#pragma unroll
        for (int j = 0; j < 4; ++j) {
            av[j] = *(const uint4*)(Ap + kt + j * 8);
            bv[j] = *(const uint4*)(Bp + kt + j * 8);
        }
        __syncthreads();
#pragma unroll
        for (int j = 0; j < 4; ++j) {
            *(uint4*)&As[srow][((shalf * 4 + j) ^ rs) * 8] = av[j];
            *(uint4*)&Bs[srow][((shalf * 4 + j) ^ rs) * 8] = bv[j];
        }
        __syncthreads();

        bf16x8 af[2][4], bfr[2][4];
#pragma unroll
        for (int kk = 0; kk < 2; ++kk)
#pragma unroll
            for (int m = 0; m < 4; ++m) {
                const int s = (kk * 4 + kg) ^ swz;
                af[kk][m]  = *(const bf16x8*)&As[wm + m * 16 + lo][s * 8];
                bfr[kk][m] = *(const bf16x8*)&Bs[wn + m * 16 + lo][s * 8];
            }
#pragma unroll
        for (int kk = 0; kk < 2; ++kk)
#pragma unroll
            for (int mt = 0; mt < 4; ++mt)
#pragma unroll
                for (int nt = 0; nt < 4; ++nt)
                    acc[mt][nt] = MFMA16(af[kk][mt], bfr[kk][nt], acc[mt][nt]);
    }

    const int col = lane & 15, r4 = (lane >> 4) * 4;
#pragma unroll
    for (int mt = 0; mt < 4; ++mt)
#pragma unroll
        for (int nt = 0; nt < 4; ++nt)
#pragma unroll
            for (int j = 0; j < 4; ++j)
                Cb[(size_t)(m0 + wm + mt * 16 + r4 + j) * DIM +
                   n0 + wn + nt * 16 + col] = f2bf(acc[mt][nt][j]);
}

// ---------------------------------------------------------------------------
// Final GEMM (NT), bf16 in, fp32 out (verified round 7)
// ---------------------------------------------------------------------------
__global__ __launch_bounds__(256)
void gemm_nt_f32o(const ushort* __restrict__ A, const ushort* __restrict__ B,
                  float* __restrict__ C, int K)
{
    __shared__ ushort As[128][64];
    __shared__ ushort Bs[128][64];

    const int nwg  = gridDim.x * gridDim.y;
    const int bid0 = blockIdx.y * gridDim.x + blockIdx.x;
    const int qq   = nwg >> 3;
    const int sbid = (bid0 & 7) * qq + (bid0 >> 3);
    const int bx   = sbid % gridDim.x, by = sbid / gridDim.x;

    const int tid  = threadIdx.x, wave = tid >> 6, lane = tid & 63;
    const int m0   = by * 128, n0 = bx * 128;
    const int lo   = lane & 15, kg = lane >> 4;
    const int wm   = (wave >> 1) * 64, wn = (wave & 1) * 64;
    const int srow = tid >> 1, shalf = tid & 1;
    const int rs   = srow & 7;
    const int swz  = lo & 7;

    f32x4 acc[4][4];
#pragma unroll
    for (int i = 0; i < 4; ++i)
#pragma unroll
        for (int j = 0; j < 4; ++j) acc[i][j] = (f32x4){0.f, 0.f, 0.f, 0.f};

    const ushort* Ap = A + (size_t)(m0 + srow) * K + shalf * 32;
    const ushort* Bp = B + (size_t)(n0 + srow) * K + shalf * 32;

    for (int kt = 0; kt < K; kt += 64) {
        uint4 av[4], bv[4];
#pragma unroll
        for (int j = 0; j < 4; ++j) {
            av[j] = *(const uint4*)(Ap + kt + j * 8);
            bv[j] = *(const uint4*)(Bp + kt + j * 8);
        }
        __syncthreads();
#pragma unroll
        for (int j = 0; j < 4; ++j) {
            *(uint4*)&As[srow][((shalf * 4 + j) ^ rs) * 8] = av[j];
            *(uint4*)&Bs[srow][((shalf * 4 + j) ^ rs) * 8] = bv[j];
        }
        __syncthreads();

        bf16x8 af[2][4], bfr[2][4];
#pragma unroll
        for (int kk = 0; kk < 2; ++kk)
#pragma unroll
            for (int m = 0; m < 4; ++m) {
                const int s = (kk * 4 + kg) ^ swz;
                af[kk][m]  = *(const bf16x8*)&As[wm + m * 16 + lo][s * 8];
                bfr[kk][m] = *(const bf16x8*)&Bs[wn + m * 16 + lo][s * 8];
            }
#pragma unroll
        for (int kk = 0; kk < 2; ++kk)
#pragma unroll
            for (int mt = 0; mt < 4; ++mt)
#pragma unroll
                for (int nt = 0; nt < 4; ++nt)
                    acc[mt][nt] = MFMA16(af[kk][mt], bfr[kk][nt], acc[mt][nt]);
    }

    const int col = lane & 15, r4 = (lane >> 4) * 4;
#pragma unroll
    for (int mt = 0; mt < 4; ++mt)
#pragma unroll
        for (int nt = 0; nt < 4; ++nt)
#pragma unroll
            for (int j = 0; j < 4; ++j)
                C[(size_t)(m0 + wm + mt * 16 + r4 + j) * DIM +
                  n0 + wn + nt * 16 + col] = acc[mt][nt][j];
}

// ---------------------------------------------------------------------------
// lr kernel (exact fp32)
// ---------------------------------------------------------------------------
__global__ __launch_bounds__(256)
void lr_kernel(const float* __restrict__ hs, const float* __restrict__ Wlr,
               float* __restrict__ LR)
{
    __shared__ float row[DIM];
    const int r = blockIdx.x;
    const int t = threadIdx.x;
    *(float4*)&row[t * 4] = *(const float4*)&hs[(size_t)r * DIM + t * 4];
    __syncthreads();

    const int o = t >> 3;
    const int p = t & 7;
    const float* w = Wlr + (size_t)o * DIM + p * 128;
    const float* x = row + p * 128;
    float acc = 0.f;
#pragma unroll
    for (int i = 0; i < 32; ++i) {
        float4 xv = *(const float4*)(x + i * 4);
        float4 wv = *(const float4*)(w + i * 4);
        acc += dot4(xv, wv);
    }
    acc += __shfl_xor(acc, 1);
    acc += __shfl_xor(acc, 2);
    acc += __shfl_xor(acc, 4);
    if (p == 0) {
        float xx = acc + 0.001f;
        LR[(size_t)r * 32 + o] = (xx > 20.f) ? xx : log1pf(expf(xx));
    }
}

// ---------------------------------------------------------------------------
// halo save (bf16)
// ---------------------------------------------------------------------------
__global__ __launch_bounds__(256)
void halo_save(const ushort* __restrict__ Q, const ushort* __restrict__ K,
               const ushort* __restrict__ V, ushort* __restrict__ HALO)
{
    int idx = blockIdx.x;
    int tn  = idx / (BATCH * (NSEG - 1) * 3);
    int rem = idx - tn * (BATCH * (NSEG - 1) * 3);
    int b   = rem / ((NSEG - 1) * 3);
    int rem2= rem - b * ((NSEG - 1) * 3);
    int s   = rem2 / 3 + 1;
    int j   = rem2 - (s - 1) * 3;

    const ushort* buf = (tn == 0) ? Q : ((tn == 1) ? K : V);
    size_t src = ((size_t)(b * SEQ + s * SEG - 3 + j)) * DIM + threadIdx.x * 4;
    size_t dst = ((size_t)((tn * BATCH + b) * NSEG + s) * 3 + j) * DIM + threadIdx.x * 4;
    *(uint2*)&HALO[dst] = *(const uint2*)&buf[src];
}

// ---------------------------------------------------------------------------
// conv in-place (bf16 buffers, fp32 math)
// ---------------------------------------------------------------------------
__global__ __launch_bounds__(256)
void conv_inplace(ushort* __restrict__ Q, ushort* __restrict__ K,
                  ushort* __restrict__ V, const ushort* __restrict__ HALO,
                  const float* __restrict__ cq, const float* __restrict__ ck,
                  const float* __restrict__ cv)
{
    const int wid  = (blockIdx.x << 2) + (threadIdx.x >> 6);
    const int lane = threadIdx.x & 63;
    const int tn   = wid >> 12;
    const int rem  = wid & 4095;
    const int b    = rem >> 10;
    const int rem2 = rem & 1023;
    const int h    = rem2 >> 6;
    const int s    = rem2 & 63;
    const int c    = (h << 6) + lane;

    ushort* buf = (tn == 0) ? Q : ((tn == 1) ? K : V);
    const float* cw = (tn == 0) ? cq : ((tn == 1) ? ck : cv);
    float4 w4 = *(const float4*)(cw + (c << 2));

    float xm3 = 0.f, xm2 = 0.f, xm1 = 0.f;
    if (s > 0) {
        size_t hb = ((size_t)((tn * BATCH + b) * NSEG + s) * 3) * DIM + c;
        xm3 = b2f(HALO[hb]);
        xm2 = b2f(HALO[hb + DIM]);
        xm1 = b2f(HALO[hb + 2 * DIM]);
    }

    size_t base = ((size_t)(b * SEQ + s * SEG)) * DIM + c;
    float x_next = b2f(buf[base]);
#pragma unroll 4
    for (int i = 0; i < SEG; ++i) {
        float x = x_next;
        if (i < SEG - 1) x_next = b2f(buf[base + (size_t)(i + 1) * DIM]);
        float y = xm3 * w4.x + xm2 * w4.y + xm1 * w4.z + x * w4.w + x;
        y = y / (1.f + __expf(-y));
        if (tn < 2) {
            float n2 = y * y;
#pragma unroll
            for (int m = 1; m < 64; m <<= 1) n2 += __shfl_xor(n2, m);
            y *= rsqrtf(n2);
        }
        buf[base + (size_t)i * DIM] = f2bf(y);
        xm3 = xm2; xm2 = xm1; xm1 = x;
    }
}

// ---------------------------------------------------------------------------
// MFMA scan: 8 blocks x 8 waves; ONE WAVE per chain (round-6 verified math),
// co-resident 2 waves/SIMD for HW latency hiding. Compact per-wave LDS
// (17.3 KB) via 4-row W/P arrays + per-lane zero-row redirect; KT[64][16] /
// VT[64][24] whose overflow k-slices are killed by partner-operand zeros.
// ---------------------------------------------------------------------------
#define OFF_KA   1152
#define OFF_VA   2304
#define OFF_SG   3456
#define OFF_KT   4608
#define OFF_VT   5632
#define OFF_WIA  7168
#define OFF_WOA  7456
#define OFF_QKT  7744
#define OFF_P0   8256
#define OFF_P1   8384
#define OFF_KH   8512
#define WSTRIDE  8640

__global__ __launch_bounds__(512)
void scan_kernel(const ushort* QP, const ushort* KP, const ushort* VP,
                 const float* LRb, const ushort* GP,
                 const float* Wi0, const float* Wo0,
                 const float* lng, const float* lnb, ushort* OB)
{
    __shared__ ushort LB[8 * WSTRIDE + 88];

    const int wid  = threadIdx.x >> 6, lane = threadIdx.x & 63;
    const int lo   = lane & 15, g = lane >> 4;
    const int chain = blockIdx.x * 8 + wid;
    const int b = chain >> 4, h = chain & 15;

    ushort* W    = LB + wid * WSTRIDE;
    ushort* uQA  = W;                  // [16][72]
    ushort* uKA  = W + OFF_KA;         // [16][72]
    ushort* uVA  = W + OFF_VA;         // [16][72]
    ushort* uSG  = W + OFF_SG;         // [16][72]
    ushort* uKT  = W + OFF_KT;         // [64][16]
    ushort* uVT  = W + OFF_VT;         // [64][24]  cols 16-19 = Wo^T
    ushort* uWIA = W + OFF_WIA;        // [4][72]
    ushort* uWOA = W + OFF_WOA;        // [4][72]
    ushort* uQKT = W + OFF_QKT;        // [16][32]
    ushort* uP0  = W + OFF_P0;         // [4][32]
    ushort* uP1  = W + OFF_P1;         // [4][32]
    ushort* uKH  = W + OFF_KH;         // [4][32]
    ushort* ZPw  = LB + 8 * WSTRIDE;   // shared zero row (each wave writes 0s)

    for (int i = lane; i < WSTRIDE; i += 64) W[i] = 0;
    for (int i = lane; i < 88; i += 64) ZPw[i] = 0;   // benign identical-value race
    const ushort* ZP = ZPw;

    f32x4 wiC[4], woC[4];
#pragma unroll
    for (int n = 0; n < 4; ++n) {
        wiC[n] = (f32x4){0.f, 0.f, 0.f, 0.f};
        woC[n] = (f32x4){0.f, 0.f, 0.f, 0.f};
    }
    if (g == 0) {
#pragma unroll
        for (int n = 0; n < 4; ++n)
#pragma unroll
            for (int D = 0; D < 4; ++D) {
                float wi = Wi0[((size_t)D * NH + h) * HD + 16 * n + lo];
                float wo = Wo0[((size_t)D * NH + h) * HD + 16 * n + lo];
                wiC[n][D] = wi; woC[n][D] = wo;
                uWIA[D * 72 + 16 * n + lo] = f2bf(wi);
                uWOA[D * 72 + 16 * n + lo] = f2bf(wo);
                uVT[(16 * n + lo) * 24 + 16 + D] = f2bf(wo);
            }
    }
    SYNC();

    float lnGr[4], lnBr[4];
#pragma unroll
    for (int n = 0; n < 4; ++n) { lnGr[n] = lng[16 * n + lo]; lnBr[n] = lnb[16 * n + lo]; }

    const ushort* QPh = QP + h * 64;
    const ushort* KPh = KP + h * 64;
    const ushort* VPh = VP + h * 64;
    const ushort* GPh = GP + h * 64;
    const float*  LRh = LRb + h * 2;
    ushort*       OBh = OB + h * 64;
    const int rowb = b * SEQ;

    uint2 pq[4], pk[4], pv[4], pg[4];
    float plr = 0.f;
    {
#pragma unroll
        for (int i = 0; i < 4; ++i) {
            size_t go = (size_t)(rowb + i * 4 + g) * DIM + 4 * lo;
            pq[i] = *(const uint2*)&QPh[go];
            pk[i] = *(const uint2*)&KPh[go];
            pv[i] = *(const uint2*)&VPh[go];
            pg[i] = *(const uint2*)&GPh[go];
        }
        if (lane < 32) plr = LRh[(size_t)(rowb + (lane >> 1)) * 32 + (lane & 1)];
    }

    const f32x4 z4 = (f32x4){0.f, 0.f, 0.f, 0.f};
    const ushort* wiRow = (lo < 4) ? (uWIA + lo * 72) : ZP;
    const ushort* woRow = (lo < 4) ? (uWOA + lo * 72) : ZP;
    const ushort* khRow = (lo < 4) ? (uKH + lo * 32) : ZP;
    const ushort* p0Row = (lo < 4) ? (uP0 + lo * 32) : ZP;
    const ushort* p1Row = (lo < 4) ? (uP1 + lo * 32) : ZP;

    for (int cc = 0; cc < NCHUNK; ++cc) {
        const int rb = rowb + cc * CHUNK_;

        // ---- stage chunk (regs -> LDS + transposed copies) ----
#pragma unroll
        for (int i = 0; i < 4; ++i) {
            const int row = i * 4 + g;
            *(uint2*)(uQA + row * 72 + 4 * lo) = pq[i];
            *(uint2*)(uKA + row * 72 + 4 * lo) = pk[i];
            *(uint2*)(uVA + row * 72 + 4 * lo) = pv[i];
            *(uint2*)(uSG + row * 72 + 4 * lo) = pg[i];
            uint2 uk = pk[i], uv = pv[i];
            uKT[(4 * lo + 0) * 16 + row] = (ushort)(uk.x & 0xFFFF);
            uKT[(4 * lo + 1) * 16 + row] = (ushort)(uk.x >> 16);
            uKT[(4 * lo + 2) * 16 + row] = (ushort)(uk.y & 0xFFFF);
            uKT[(4 * lo + 3) * 16 + row] = (ushort)(uk.y >> 16);
            uVT[(4 * lo + 0) * 24 + row] = (ushort)(uv.x & 0xFFFF);
            uVT[(4 * lo + 1) * 24 + row] = (ushort)(uv.x >> 16);
            uVT[(4 * lo + 2) * 24 + row] = (ushort)(uv.y & 0xFFFF);
            uVT[(4 * lo + 3) * 24 + row] = (ushort)(uv.y >> 16);
        }
        const float lr1    = __shfl(plr, 2 * lo + 1);
        const float lr_in  = __shfl(plr, 0);
        const float lr_out = __shfl(plr, 1);

        // ---- prefetch next chunk ----
        if (cc + 1 < NCHUNK) {
            const int rb2 = rb + CHUNK_;
#pragma unroll
            for (int i = 0; i < 4; ++i) {
                size_t go = (size_t)(rb2 + i * 4 + g) * DIM + 4 * lo;
                pq[i] = *(const uint2*)&QPh[go];
                pk[i] = *(const uint2*)&KPh[go];
                pv[i] = *(const uint2*)&VPh[go];
                pg[i] = *(const uint2*)&GPh[go];
            }
            if (lane < 32) plr = LRh[(size_t)(rb2 + (lane >> 1)) * 32 + (lane & 1)];
        }
        SYNC();

        // ---- M1/M2: logits^T ----
        bf16x8 xWi0 = *(const bf16x8*)(wiRow + g * 8);
        bf16x8 xWi1 = *(const bf16x8*)(wiRow + g * 8 + 32);
        f32x4 cK = MFMA16(xWi0, *(const bf16x8*)(uKA + lo * 72 + g * 8), z4);
        cK = MFMA16(xWi1, *(const bf16x8*)(uKA + lo * 72 + g * 8 + 32), cK);
        f32x4 cQ = MFMA16(xWi0, *(const bf16x8*)(uQA + lo * 72 + g * 8), z4);
        cQ = MFMA16(xWi1, *(const bf16x8*)(uQA + lo * 72 + g * 8 + 32), cQ);

        // ---- softmax over D (register-local) ----
        float mK = fmaxf(fmaxf(cK[0], cK[1]), fmaxf(cK[2], cK[3]));
        float ek0 = __expf(cK[0] - mK), ek1 = __expf(cK[1] - mK);
        float ek2 = __expf(cK[2] - mK), ek3 = __expf(cK[3] - mK);
        float ivk = lr1 / (ek0 + ek1 + ek2 + ek3);
        float kh0 = ek0 * ivk, kh1 = ek1 * ivk, kh2 = ek2 * ivk, kh3 = ek3 * ivk;

        float mQ = fmaxf(fmaxf(cQ[0], cQ[1]), fmaxf(cQ[2], cQ[3]));
        float eq0 = __expf(cQ[0] - mQ), eq1 = __expf(cQ[1] - mQ);
        float eq2 = __expf(cQ[2] - mQ), eq3 = __expf(cQ[3] - mQ);
        float ivq = 1.f / (eq0 + eq1 + eq2 + eq3);
        float qh0 = eq0 * ivq, qh1 = eq1 * ivq, qh2 = eq2 * ivq, qh3 = eq3 * ivq;

        // ---- M3: qk (pure-register) ----
        B8 aQh, bKh;
        aQh.u[0] = aQh.u[1] = aQh.u[2] = aQh.u[3] = 0;
        bKh.u[0] = bKh.u[1] = bKh.u[2] = bKh.u[3] = 0;
        if (g == 0) {
            aQh.u[0] = pack2(qh0, qh1); aQh.u[1] = pack2(qh2, qh3);
            bKh.u[0] = pack2(kh0, kh1); bKh.u[1] = pack2(kh2, kh3);
        }
        f32x4 cQK = MFMA16(aQh.v, bKh.v, z4);

        // ---- bounce qk (tril) + q_h + kh ----
#pragma unroll
        for (int r = 0; r < 4; ++r) {
            const int q = 4 * g + r;
            uQKT[q * 32 + lo] = (lo <= q) ? f2bf(cQK[r]) : (ushort)0;
        }
        if (g == 0) {
            uQKT[lo * 32 + 16] = f2bf(qh0); uQKT[lo * 32 + 17] = f2bf(qh1);
            uQKT[lo * 32 + 18] = f2bf(qh2); uQKT[lo * 32 + 19] = f2bf(qh3);
            uKH[0 * 32 + lo] = f2bf(kh0); uKH[1 * 32 + lo] = f2bf(kh1);
            uKH[2 * 32 + lo] = f2bf(kh2); uKH[3 * 32 + lo] = f2bf(kh3);
        }
        SYNC();

        // ---- M4: o = qk_ext @ [V | Wo] ; LN + gate + store ----
        bf16x8 aO = *(const bf16x8*)(uQKT + lo * 32 + g * 8);
        f32x4 oA[4];
#pragma unroll
        for (int n = 0; n < 4; ++n)
            oA[n] = MFMA16(aO, *(const bf16x8*)(uVT + (16 * n + lo) * 24 + g * 8), z4);
#pragma unroll
        for (int r = 0; r < 4; ++r) {
            float s1 = oA[0][r] + oA[1][r] + oA[2][r] + oA[3][r];
            float s2 = oA[0][r] * oA[0][r] + oA[1][r] * oA[1][r] +
                       oA[2][r] * oA[2][r] + oA[3][r] * oA[3][r];
            s1 = redsum16(s1); s2 = redsum16(s2);
            float mu = s1 * (1.f / 64.f);
            float rstd = rsqrtf(s2 * (1.f / 64.f) - mu * mu + 1e-5f);
            const int q = 4 * g + r;
#pragma unroll
            for (int n = 0; n < 4; ++n) {
                float val = (oA[n][r] - mu) * rstd * lnGr[n] + lnBr[n];
                val *= b2f(uSG[q * 72 + 16 * n + lo]);
                OBh[(size_t)(rb + q) * DIM + 16 * n + lo] = f2bf(val);
            }
        }

        // ---- update1: W_out += k_h^T @ V ----
        {
            bf16x8 aKH = *(const bf16x8*)(khRow + g * 8);
#pragma unroll
            for (int n = 0; n < 4; ++n)
                woC[n] = MFMA16(aKH, *(const bf16x8*)(uVT + (16 * n + lo) * 24 + g * 8),
                                woC[n]);
        }
        if (g == 0) {
#pragma unroll
            for (int n = 0; n < 4; ++n)
#pragma unroll
                for (int D = 0; D < 4; ++D)
                    uWOA[D * 72 + 16 * n + lo] = f2bf(woC[n][D]);
        }
        SYNC();

        // ---- inner TTT loop (2 iters) ----
#pragma unroll
        for (int it = 0; it < 2; ++it) {
            f32x4 s0v;
            if (it == 0) {
                s0v = cK;                      // Wi unchanged since logits
            } else {
                bf16x8 y0 = *(const bf16x8*)(wiRow + g * 8);
                bf16x8 y1 = *(const bf16x8*)(wiRow + g * 8 + 32);
                s0v = MFMA16(y0, *(const bf16x8*)(uKA + lo * 72 + g * 8), z4);
                s0v = MFMA16(y1, *(const bf16x8*)(uKA + lo * 72 + g * 8 + 32), s0v);
            }
            bf16x8 w0 = *(const bf16x8*)(woRow + g * 8);
            bf16x8 w1 = *(const bf16x8*)(woRow + g * 8 + 32);
            f32x4 s1v = MFMA16(w0, *(const bf16x8*)(uVA + lo * 72 + g * 8), z4);
            s1v = MFMA16(w1, *(const bf16x8*)(uVA + lo * 72 + g * 8 + 32), s1v);

            float p0v[4], p1v[4];
#pragma unroll
            for (int r = 0; r < 4; ++r) {
                float x0 = s0v[r] * 0.125f, x1 = s1v[r] * 0.125f;
                float m0v = redmax16(x0), m1v = redmax16(x1);
                float e0 = __expf(x0 - m0v), e1 = __expf(x1 - m1v);
                p0v[r] = e0 / redsum16(e0);
                p1v[r] = e1 / redsum16(e1);
            }
            if (g == 0) {
#pragma unroll
                for (int r = 0; r < 4; ++r) {
                    uP0[r * 32 + lo] = f2bf(p0v[r] * lr_out);
                    uP1[r * 32 + lo] = f2bf(p1v[r] * lr_in);
                }
            }
            SYNC();

            bf16x8 aP0 = *(const bf16x8*)(p0Row + g * 8);
            bf16x8 aP1 = *(const bf16x8*)(p1Row + g * 8);
#pragma unroll
            for (int n = 0; n < 4; ++n) {
                woC[n] = MFMA16(aP0, *(const bf16x8*)(uVT + (16 * n + lo) * 24 + g * 8),
                                woC[n]);
                wiC[n] = MFMA16(aP1, *(const bf16x8*)(uKT + (16 * n + lo) * 16 + g * 8),
                                wiC[n]);
            }
            if (g == 0) {
#pragma unroll
                for (int n = 0; n < 4; ++n)
#pragma unroll
                    for (int D = 0; D < 4; ++D) {
                        uWIA[D * 72 + 16 * n + lo] = f2bf(wiC[n][D]);
                        uWOA[D * 72 + 16 * n + lo] = f2bf(woC[n][D]);
                        if (it == 1) uVT[(16 * n + lo) * 24 + 16 + D] = f2bf(woC[n][D]);
                    }
            }
            SYNC();
        }
    }
}

// ---------------------------------------------------------------------------
// launch
// ---------------------------------------------------------------------------
extern "C" void kernel_launch(void* const* d_in, const int* in_sizes, int n_in,
                              void* d_out, int out_size, void* d_ws, size_t ws_size,
                              hipStream_t stream)
{
    const float* hs  = (const float*)d_in[0];
    const float* Wq  = (const float*)d_in[1];
    const float* Wk  = (const float*)d_in[2];
    const float* Wv  = (const float*)d_in[3];
    const float* Wlr = (const float*)d_in[4];
    const float* Wg  = (const float*)d_in[5];
    const float* Wo  = (const float*)d_in[6];
    const float* cq  = (const float*)d_in[7];
    const float* ck  = (const float*)d_in[8];
    const float* cv  = (const float*)d_in[9];
    const float* Wi0 = (const float*)d_in[10];
    const float* Wo0 = (const float*)d_in[11];
    const float* lng = (const float*)d_in[12];
    const float* lnb = (const float*)d_in[13];

    ushort* Qb  = (ushort*)d_ws;
    ushort* Kb  = Qb + (size_t)NROWS * DIM;
    ushort* Vb  = Kb + (size_t)NROWS * DIM;
    ushort* Gb  = Vb + (size_t)NROWS * DIM;
    ushort* hsb = Gb + (size_t)NROWS * DIM;
    ushort* Wqb = hsb + (size_t)NROWS * DIM;
    ushort* Wkb = Wqb + (size_t)DIM * DIM;
    ushort* Wvb = Wkb + (size_t)DIM * DIM;
    ushort* Wgb = Wvb + (size_t)DIM * DIM;
    ushort* Wob = Wgb + (size_t)DIM * DIM;
    ushort* HALO = Wob + (size_t)DIM * DIM;
    float*  LRb  = (float*)(HALO + (size_t)3 * BATCH * NSEG * 3 * DIM);
    ushort* OBUF = hsb;   // hs bf16 dead after projections (stream-ordered)

    dim3 blk(256);

    f2b_kernel<<<2048, blk, 0, stream>>>(hs, hsb, NROWS * DIM / 8);
    f2b_kernel<<<512, blk, 0, stream>>>(Wq, Wqb, DIM * DIM / 8);
    f2b_kernel<<<512, blk, 0, stream>>>(Wk, Wkb, DIM * DIM / 8);
    f2b_kernel<<<512, blk, 0, stream>>>(Wv, Wvb, DIM * DIM / 8);
    f2b_kernel<<<512, blk, 0, stream>>>(Wg, Wgb, DIM * DIM / 8);
    f2b_kernel<<<512, blk, 0, stream>>>(Wo, Wob, DIM * DIM / 8);

    // fused q|k|v|gate projection
    gemm_nt_bf16o<<<dim3(32, 128), blk, 0, stream>>>(hsb, Wqb, Qb, 1024);

    lr_kernel<<<NROWS, blk, 0, stream>>>(hs, Wlr, LRb);

    halo_save<<<3 * BATCH * (NSEG - 1) * 3, blk, 0, stream>>>(Qb, Kb, Vb, HALO);
    conv_inplace<<<(3 * BATCH * NH * NSEG) / 4, blk, 0, stream>>>(Qb, Kb, Vb, HALO,
                                                                  cq, ck, cv);

    scan_kernel<<<8, dim3(512), 0, stream>>>(Qb, Kb, Vb, LRb, Gb,
                                             Wi0, Wo0, lng, lnb, OBUF);

    gemm_nt_f32o<<<dim3(8, 128), blk, 0, stream>>>(OBUF, Wob, (float*)d_out, 1024);
}

// Round 9
// 2132.406 us; speedup vs baseline: 1.9148x; 1.7163x over previous
//
#include <hip/hip_runtime.h>
#include <cstdint>
#include <cstddef>

#define DIM    1024
#define NH     16
#define HD     64
#define CHUNK_ 16
#define SEQ    4096
#define BATCH  4
#define NROWS  (BATCH * SEQ)       // 16384
#define NCHUNK (SEQ / CHUNK_)      // 256
#define SEG    64
#define NSEG   (SEQ / SEG)         // 64

using bf16x8 = __attribute__((ext_vector_type(8))) short;
using f32x4  = __attribute__((ext_vector_type(4))) float;
typedef union { bf16x8 v; uint32_t u[4]; } B8;

#define MFMA16(a, b, c) __builtin_amdgcn_mfma_f32_16x16x32_bf16((a), (b), (c), 0, 0, 0)

__device__ __forceinline__ ushort f2bf(float f) {
    uint32_t u = __float_as_uint(f);
    u += 0x7FFFu + ((u >> 16) & 1u);      // RTNE
    return (ushort)(u >> 16);
}
__device__ __forceinline__ uint32_t pack2(float a, float b) {
    return (uint32_t)f2bf(a) | ((uint32_t)f2bf(b) << 16);
}
__device__ __forceinline__ float dot4(const float4 a, const float4 b) {
    return a.x*b.x + a.y*b.y + a.z*b.z + a.w*b.w;
}
__device__ __forceinline__ float redsum16(float x) {
    x += __shfl_xor(x, 1); x += __shfl_xor(x, 2);
    x += __shfl_xor(x, 4); x += __shfl_xor(x, 8);
    return x;
}

// single-wave "barrier": compiler-only fence (verified rounds 6-8)
#define SYNC() do { asm volatile("" ::: "memory");          \
                    __builtin_amdgcn_wave_barrier();        \
                    __builtin_amdgcn_sched_barrier(0); } while (0)

// ---------------------------------------------------------------------------
// bf16 MFMA GEMM (NT): fp32 in, inline RTNE pack, fp32 out. (R4-verified;
// best measured non-scan pipeline.) 128x128 tile, BK=32, 4 waves.
// ---------------------------------------------------------------------------
__global__ __launch_bounds__(256)
void gemm_nt_bf16(const float* __restrict__ A, const float* __restrict__ B,
                  float* __restrict__ C, int K, int ldc)
{
    __shared__ ushort As[128][64];
    __shared__ ushort Bs[128][64];

    const int tid  = threadIdx.x;
    const int m0   = blockIdx.y * 128, n0 = blockIdx.x * 128;
    const int wave = tid >> 6, lane = tid & 63;
    const int wm   = (wave >> 1) * 64, wn = (wave & 1) * 64;
    const int frow = lane & 15, fkg = lane >> 4;
    const int srow = tid >> 1, shalf = tid & 1;

    f32x4 acc[4][4];
#pragma unroll
    for (int i = 0; i < 4; ++i)
#pragma unroll
        for (int j = 0; j < 4; ++j) acc[i][j] = (f32x4){0.f, 0.f, 0.f, 0.f};

    const float* Ap0 = A + (size_t)(m0 + srow) * K + shalf * 16;
    const float* Bp0 = B + (size_t)(n0 + srow) * K + shalf * 16;
    const int swz0 = ((shalf * 2 + 0) ^ (srow & 7)) * 8;
    const int swz1 = ((shalf * 2 + 1) ^ (srow & 7)) * 8;
    const int rsw  = (frow & 7);

    for (int kt = 0; kt < K; kt += 32) {
        float4 a0 = *(const float4*)(Ap0 + kt);
        float4 a1 = *(const float4*)(Ap0 + kt + 4);
        float4 a2 = *(const float4*)(Ap0 + kt + 8);
        float4 a3 = *(const float4*)(Ap0 + kt + 12);
        float4 b0 = *(const float4*)(Bp0 + kt);
        float4 b1 = *(const float4*)(Bp0 + kt + 4);
        float4 b2 = *(const float4*)(Bp0 + kt + 8);
        float4 b3 = *(const float4*)(Bp0 + kt + 12);

        __syncthreads();
        uint4 u;
        u.x = pack2(a0.x, a0.y); u.y = pack2(a0.z, a0.w);
        u.z = pack2(a1.x, a1.y); u.w = pack2(a1.z, a1.w);
        *(uint4*)&As[srow][swz0] = u;
        u.x = pack2(a2.x, a2.y); u.y = pack2(a2.z, a2.w);
        u.z = pack2(a3.x, a3.y); u.w = pack2(a3.z, a3.w);
        *(uint4*)&As[srow][swz1] = u;
        u.x = pack2(b0.x, b0.y); u.y = pack2(b0.z, b0.w);
        u.z = pack2(b1.x, b1.y); u.w = pack2(b1.z, b1.w);
        *(uint4*)&Bs[srow][swz0] = u;
        u.x = pack2(b2.x, b2.y); u.y = pack2(b2.z, b2.w);
        u.z = pack2(b3.x, b3.y); u.w = pack2(b3.z, b3.w);
        *(uint4*)&Bs[srow][swz1] = u;
        __syncthreads();

        bf16x8 af[4], bf[4];
#pragma unroll
        for (int i = 0; i < 4; ++i) {
            af[i] = *(const bf16x8*)&As[wm + i * 16 + frow][(fkg ^ rsw) * 8];
            bf[i] = *(const bf16x8*)&Bs[wn + i * 16 + frow][(fkg ^ rsw) * 8];
        }
#pragma unroll
        for (int mt = 0; mt < 4; ++mt)
#pragma unroll
            for (int nt = 0; nt < 4; ++nt)
                acc[mt][nt] = MFMA16(af[mt], bf[nt], acc[mt][nt]);
    }

    const int col = lane & 15, r4 = (lane >> 4) * 4;
#pragma unroll
    for (int mt = 0; mt < 4; ++mt)
#pragma unroll
        for (int nt = 0; nt < 4; ++nt)
#pragma unroll
            for (int j = 0; j < 4; ++j)
                C[(size_t)(m0 + wm + mt * 16 + r4 + j) * ldc +
                  (n0 + wn + nt * 16 + col)] = acc[mt][nt][j];
}

// ---------------------------------------------------------------------------
// lr kernel (exact fp32)
// ---------------------------------------------------------------------------
__global__ __launch_bounds__(256)
void lr_kernel(const float* __restrict__ hs, const float* __restrict__ Wlr,
               float* __restrict__ LR)
{
    __shared__ float row[DIM];
    const int r = blockIdx.x;
    const int t = threadIdx.x;
    *(float4*)&row[t * 4] = *(const float4*)&hs[(size_t)r * DIM + t * 4];
    __syncthreads();

    const int o = t >> 3;
    const int p = t & 7;
    const float* w = Wlr + (size_t)o * DIM + p * 128;
    const float* x = row + p * 128;
    float acc = 0.f;
#pragma unroll
    for (int i = 0; i < 32; ++i) {
        float4 xv = *(const float4*)(x + i * 4);
        float4 wv = *(const float4*)(w + i * 4);
        acc += dot4(xv, wv);
    }
    acc += __shfl_xor(acc, 1);
    acc += __shfl_xor(acc, 2);
    acc += __shfl_xor(acc, 4);
    if (p == 0) {
        float xx = acc + 0.001f;
        LR[(size_t)r * 32 + o] = (xx > 20.f) ? xx : log1pf(expf(xx));
    }
}

// ---------------------------------------------------------------------------
// halo save (fp32, R4-verified)
// ---------------------------------------------------------------------------
__global__ __launch_bounds__(256)
void halo_save(const float* __restrict__ Q, const float* __restrict__ K,
               const float* __restrict__ V, float* __restrict__ HALO)
{
    int idx = blockIdx.x;
    int tn  = idx / (BATCH * (NSEG - 1) * 3);
    int rem = idx - tn * (BATCH * (NSEG - 1) * 3);
    int b   = rem / ((NSEG - 1) * 3);
    int rem2= rem - b * ((NSEG - 1) * 3);
    int s   = rem2 / 3 + 1;
    int j   = rem2 - (s - 1) * 3;

    const float* buf = (tn == 0) ? Q : ((tn == 1) ? K : V);
    size_t src = ((size_t)(b * SEQ + s * SEG - 3 + j)) * DIM + threadIdx.x * 4;
    size_t dst = ((size_t)((tn * BATCH + b) * NSEG + s) * 3 + j) * DIM + threadIdx.x * 4;
    *(float4*)&HALO[dst] = *(const float4*)&buf[src];
}

// ---------------------------------------------------------------------------
// conv in-place (fp32, R4-verified)
// ---------------------------------------------------------------------------
__global__ __launch_bounds__(256)
void conv_inplace(float* __restrict__ Q, float* __restrict__ K,
                  float* __restrict__ V, const float* __restrict__ HALO,
                  const float* __restrict__ cq, const float* __restrict__ ck,
                  const float* __restrict__ cv)
{
    const int wid  = (blockIdx.x << 2) + (threadIdx.x >> 6);
    const int lane = threadIdx.x & 63;
    const int tn   = wid >> 12;
    const int rem  = wid & 4095;
    const int b    = rem >> 10;
    const int rem2 = rem & 1023;
    const int h    = rem2 >> 6;
    const int s    = rem2 & 63;
    const int c    = (h << 6) + lane;

    float* buf = (tn == 0) ? Q : ((tn == 1) ? K : V);
    const float* cw = (tn == 0) ? cq : ((tn == 1) ? ck : cv);
    float4 w4 = *(const float4*)(cw + (c << 2));

    float xm3 = 0.f, xm2 = 0.f, xm1 = 0.f;
    if (s > 0) {
        size_t hb = ((size_t)((tn * BATCH + b) * NSEG + s) * 3) * DIM + c;
        xm3 = HALO[hb];
        xm2 = HALO[hb + DIM];
        xm1 = HALO[hb + 2 * DIM];
    }

    size_t base = ((size_t)(b * SEQ + s * SEG)) * DIM + c;
    float x_next = buf[base];
#pragma unroll 4
    for (int i = 0; i < SEG; ++i) {
        float x = x_next;
        if (i < SEG - 1) x_next = buf[base + (size_t)(i + 1) * DIM];
        float y = xm3 * w4.x + xm2 * w4.y + xm1 * w4.z + x * w4.w + x;
        y = y / (1.f + __expf(-y));
        if (tn < 2) {
            float n2 = y * y;
#pragma unroll
            for (int m = 1; m < 64; m <<= 1) n2 += __shfl_xor(n2, m);
            y *= rsqrtf(n2);
        }
        buf[base + (size_t)i * DIM] = y;
        xm3 = xm2; xm2 = xm1; xm1 = x;
    }
}

// ---------------------------------------------------------------------------
// MFMA scan, barrier-free, ONE WAVE per (b,h) chain, 64 blocks (R6-verified
// structure). One change vs R6: inner-loop scores computed TRANSPOSED
// (MFMA(K,Wi)/MFMA(V,Wo) -> j in registers), so the j-softmax reduction is
// 3 reg-fmax + 2 shfls instead of 8-deep shfl chains. fp32 in/out.
// ---------------------------------------------------------------------------
__global__ __launch_bounds__(64)
void scan_kernel(const float* QP, const float* __restrict__ KP,
                 const float* __restrict__ VP, const float* __restrict__ LRb,
                 const float* __restrict__ GATE,
                 const float* __restrict__ Wi0, const float* __restrict__ Wo0,
                 const float* __restrict__ lng, const float* __restrict__ lnb,
                 float* OB)
{
    const int bh = blockIdx.x, b = bh >> 4, h = bh & 15;
    const int t  = threadIdx.x, lo = t & 15, g = t >> 4;

    __shared__ ushort KA[16][72], QA[16][72], VA[16][72];   // rows [l][d]
    __shared__ ushort KT[64][24];                           // K^T [d][l]
    __shared__ ushort VT[64][40];                           // [d][V^T | Wo^T | 0]
    __shared__ ushort WiA[16][72], WoA[16][72];             // [D][d], rows 4+ zero
    __shared__ ushort QKT[16][32];                          // [q][qk | q_h | 0]
    __shared__ ushort P0s[16][32], P1s[16][32], KH[16][32];
    __shared__ float  sG[16][68];

    for (int i = t; i < 16 * 72; i += 64) { ((ushort*)WiA)[i] = 0; ((ushort*)WoA)[i] = 0; }
    for (int i = t; i < 64 * 24; i += 64) ((ushort*)KT)[i] = 0;
    for (int i = t; i < 64 * 40; i += 64) ((ushort*)VT)[i] = 0;
    for (int i = t; i < 16 * 32; i += 64) {
        ((ushort*)QKT)[i] = 0; ((ushort*)P0s)[i] = 0;
        ((ushort*)P1s)[i] = 0; ((ushort*)KH)[i]  = 0;
    }

    f32x4 wiC[4], woC[4];
#pragma unroll
    for (int n = 0; n < 4; ++n) { wiC[n] = (f32x4){0,0,0,0}; woC[n] = (f32x4){0,0,0,0}; }
    if (g == 0) {
#pragma unroll
        for (int n = 0; n < 4; ++n)
#pragma unroll
            for (int D = 0; D < 4; ++D) {
                float wi = Wi0[((size_t)D * NH + h) * HD + 16 * n + lo];
                float wo = Wo0[((size_t)D * NH + h) * HD + 16 * n + lo];
                wiC[n][D] = wi; woC[n][D] = wo;
                WiA[D][16 * n + lo] = f2bf(wi);
                WoA[D][16 * n + lo] = f2bf(wo);
                VT[16 * n + lo][16 + D] = f2bf(wo);
            }
    }
    SYNC();

    float lnGr[4], lnBr[4];
#pragma unroll
    for (int n = 0; n < 4; ++n) { lnGr[n] = lng[16 * n + lo]; lnBr[n] = lnb[16 * n + lo]; }

    const int rowb = b * SEQ;
    float4 pq[4], pk[4], pv[4], pg[4];
    float plr = 0.f;
    {
#pragma unroll
        for (int i = 0; i < 4; ++i) {
            size_t go = (size_t)(rowb + i * 4 + g) * DIM + h * 64 + 4 * lo;
            pq[i] = *(const float4*)&QP[go];
            pk[i] = *(const float4*)&KP[go];
            pv[i] = *(const float4*)&VP[go];
            pg[i] = *(const float4*)&GATE[go];
        }
        if (t < 32) plr = LRb[(size_t)(rowb + (t >> 1)) * 32 + h * 2 + (t & 1)];
    }

    const f32x4 z4 = (f32x4){0.f, 0.f, 0.f, 0.f};

    for (int c = 0; c < NCHUNK; ++c) {
        const int rb = rowb + c * CHUNK_;

        // ---- stage chunk (regs -> LDS, bf16 + transposed copies) ----
#pragma unroll
        for (int i = 0; i < 4; ++i) {
            const int row = i * 4 + g;
            *(float4*)&sG[row][4 * lo] = pg[i];
            uint2 uq; uq.x = pack2(pq[i].x, pq[i].y); uq.y = pack2(pq[i].z, pq[i].w);
            *(uint2*)&QA[row][4 * lo] = uq;
            uint2 uk; uk.x = pack2(pk[i].x, pk[i].y); uk.y = pack2(pk[i].z, pk[i].w);
            *(uint2*)&KA[row][4 * lo] = uk;
            uint2 uv; uv.x = pack2(pv[i].x, pv[i].y); uv.y = pack2(pv[i].z, pv[i].w);
            *(uint2*)&VA[row][4 * lo] = uv;
            KT[4 * lo + 0][row] = (ushort)(uk.x & 0xFFFF);
            KT[4 * lo + 1][row] = (ushort)(uk.x >> 16);
            KT[4 * lo + 2][row] = (ushort)(uk.y & 0xFFFF);
            KT[4 * lo + 3][row] = (ushort)(uk.y >> 16);
            VT[4 * lo + 0][row] = (ushort)(uv.x & 0xFFFF);
            VT[4 * lo + 1][row] = (ushort)(uv.x >> 16);
            VT[4 * lo + 2][row] = (ushort)(uv.y & 0xFFFF);
            VT[4 * lo + 3][row] = (ushort)(uv.y >> 16);
        }
        const float lr1    = __shfl(plr, 2 * lo + 1);
        const float lr_in  = __shfl(plr, 0);
        const float lr_out = __shfl(plr, 1);

        // ---- prefetch next chunk ----
        if (c + 1 < NCHUNK) {
            const int rb2 = rb + CHUNK_;
#pragma unroll
            for (int i = 0; i < 4; ++i) {
                size_t go = (size_t)(rb2 + i * 4 + g) * DIM + h * 64 + 4 * lo;
                pq[i] = *(const float4*)&QP[go];
                pk[i] = *(const float4*)&KP[go];
                pv[i] = *(const float4*)&VP[go];
                pg[i] = *(const float4*)&GATE[go];
            }
            if (t < 32) plr = LRb[(size_t)(rb2 + (t >> 1)) * 32 + h * 2 + (t & 1)];
        }
        SYNC();

        // ---- M1/M2: logits^T  cK[D][l], cQ[D][l] (valid lanes 0-15) ----
        bf16x8 xWi0 = *(const bf16x8*)&WiA[lo][g * 8];
        bf16x8 xWi1 = *(const bf16x8*)&WiA[lo][g * 8 + 32];
        f32x4 cK = MFMA16(xWi0, *(const bf16x8*)&KA[lo][g * 8], z4);
        cK = MFMA16(xWi1, *(const bf16x8*)&KA[lo][g * 8 + 32], cK);
        f32x4 cQ = MFMA16(xWi0, *(const bf16x8*)&QA[lo][g * 8], z4);
        cQ = MFMA16(xWi1, *(const bf16x8*)&QA[lo][g * 8 + 32], cQ);

        // ---- softmax over D: register-local ----
        float mK = fmaxf(fmaxf(cK[0], cK[1]), fmaxf(cK[2], cK[3]));
        float ek0 = __expf(cK[0] - mK), ek1 = __expf(cK[1] - mK);
        float ek2 = __expf(cK[2] - mK), ek3 = __expf(cK[3] - mK);
        float ivk = lr1 / (ek0 + ek1 + ek2 + ek3);
        float kh0 = ek0 * ivk, kh1 = ek1 * ivk, kh2 = ek2 * ivk, kh3 = ek3 * ivk;

        float mQ = fmaxf(fmaxf(cQ[0], cQ[1]), fmaxf(cQ[2], cQ[3]));
        float eq0 = __expf(cQ[0] - mQ), eq1 = __expf(cQ[1] - mQ);
        float eq2 = __expf(cQ[2] - mQ), eq3 = __expf(cQ[3] - mQ);
        float ivq = 1.f / (eq0 + eq1 + eq2 + eq3);
        float qh0 = eq0 * ivq, qh1 = eq1 * ivq, qh2 = eq2 * ivq, qh3 = eq3 * ivq;

        // ---- M3: qk = q_h @ k_h^T (pure-register) ----
        B8 aQh, bKh;
        aQh.u[0] = aQh.u[1] = aQh.u[2] = aQh.u[3] = 0;
        bKh.u[0] = bKh.u[1] = bKh.u[2] = bKh.u[3] = 0;
        if (g == 0) {
            aQh.u[0] = pack2(qh0, qh1); aQh.u[1] = pack2(qh2, qh3);
            bKh.u[0] = pack2(kh0, kh1); bKh.u[1] = pack2(kh2, kh3);
        }
        f32x4 cQK = MFMA16(aQh.v, bKh.v, z4);

        // ---- bounce qk (tril) + q_h + kh ----
#pragma unroll
        for (int r = 0; r < 4; ++r) {
            const int q = 4 * g + r;
            QKT[q][lo] = (lo <= q) ? f2bf(cQK[r]) : (ushort)0;
        }
        if (g == 0) {
            QKT[lo][16] = f2bf(qh0); QKT[lo][17] = f2bf(qh1);
            QKT[lo][18] = f2bf(qh2); QKT[lo][19] = f2bf(qh3);
            KH[0][lo] = f2bf(kh0); KH[1][lo] = f2bf(kh1);
            KH[2][lo] = f2bf(kh2); KH[3][lo] = f2bf(kh3);
        }
        SYNC();

        // ---- M4: o = qk_ext @ [V | Wo] ; LN + gate + fp32 store ----
        bf16x8 aO = *(const bf16x8*)&QKT[lo][g * 8];
        f32x4 oA[4];
#pragma unroll
        for (int n = 0; n < 4; ++n)
            oA[n] = MFMA16(aO, *(const bf16x8*)&VT[16 * n + lo][g * 8], z4);
#pragma unroll
        for (int r = 0; r < 4; ++r) {
            float s1 = oA[0][r] + oA[1][r] + oA[2][r] + oA[3][r];
            float s2 = oA[0][r] * oA[0][r] + oA[1][r] * oA[1][r] +
                       oA[2][r] * oA[2][r] + oA[3][r] * oA[3][r];
            s1 = redsum16(s1); s2 = redsum16(s2);
            float mu = s1 * (1.f / 64.f);
            float rstd = rsqrtf(s2 * (1.f / 64.f) - mu * mu + 1e-5f);
            const int q = 4 * g + r;
#pragma unroll
            for (int n = 0; n < 4; ++n) {
                float val = (oA[n][r] - mu) * rstd * lnGr[n] + lnBr[n];
                val *= sG[q][16 * n + lo];
                OB[(size_t)(rb + q) * DIM + h * 64 + 16 * n + lo] = val;
            }
        }

        // ---- update1: W_out += k_h^T @ V ----
        {
            bf16x8 aKH = *(const bf16x8*)&KH[lo][g * 8];
#pragma unroll
            for (int n = 0; n < 4; ++n)
                woC[n] = MFMA16(aKH, *(const bf16x8*)&VT[16 * n + lo][g * 8], woC[n]);
        }
        if (g == 0) {
#pragma unroll
            for (int n = 0; n < 4; ++n)
#pragma unroll
                for (int D = 0; D < 4; ++D)
                    WoA[D][16 * n + lo] = f2bf(woC[n][D]);
        }
        SYNC();

        // ---- inner TTT loop (2 iters), TRANSPOSED scores ----
#pragma unroll
        for (int it = 0; it < 2; ++it) {
            // sT[j=4g+r][D=lo]: X = K/V rows (j), Y = Wi/Wo rows (D; rows 4+ zero)
            bf16x8 aK0 = *(const bf16x8*)&KA[lo][g * 8];
            bf16x8 aK1 = *(const bf16x8*)&KA[lo][g * 8 + 32];
            bf16x8 aV0 = *(const bf16x8*)&VA[lo][g * 8];
            bf16x8 aV1 = *(const bf16x8*)&VA[lo][g * 8 + 32];
            bf16x8 bWi0 = *(const bf16x8*)&WiA[lo][g * 8];
            bf16x8 bWi1 = *(const bf16x8*)&WiA[lo][g * 8 + 32];
            bf16x8 bWo0 = *(const bf16x8*)&WoA[lo][g * 8];
            bf16x8 bWo1 = *(const bf16x8*)&WoA[lo][g * 8 + 32];
            f32x4 s0T = MFMA16(aK0, bWi0, z4);
            s0T = MFMA16(aK1, bWi1, s0T);
            f32x4 s1T = MFMA16(aV0, bWo0, z4);
            s1T = MFMA16(aV1, bWo1, s1T);

            // softmax over j: regs (r) + lane-groups (g) -> 2 shfls
            float x0[4], x1[4];
#pragma unroll
            for (int r = 0; r < 4; ++r) {
                x0[r] = s0T[r] * 0.125f;
                x1[r] = s1T[r] * 0.125f;
            }
            float m0 = fmaxf(fmaxf(x0[0], x0[1]), fmaxf(x0[2], x0[3]));
            float m1 = fmaxf(fmaxf(x1[0], x1[1]), fmaxf(x1[2], x1[3]));
            m0 = fmaxf(m0, __shfl_xor(m0, 16)); m0 = fmaxf(m0, __shfl_xor(m0, 32));
            m1 = fmaxf(m1, __shfl_xor(m1, 16)); m1 = fmaxf(m1, __shfl_xor(m1, 32));
            float e0[4], e1[4];
#pragma unroll
            for (int r = 0; r < 4; ++r) {
                e0[r] = __expf(x0[r] - m0);
                e1[r] = __expf(x1[r] - m1);
            }
            float su0 = e0[0] + e0[1] + e0[2] + e0[3];
            float su1 = e1[0] + e1[1] + e1[2] + e1[3];
            su0 += __shfl_xor(su0, 16); su0 += __shfl_xor(su0, 32);
            su1 += __shfl_xor(su1, 16); su1 += __shfl_xor(su1, 32);
            const float w0 = lr_out / su0;
            const float w1 = lr_in / su1;
            if (lo < 4) {
#pragma unroll
                for (int r = 0; r < 4; ++r) {
                    P0s[lo][4 * g + r] = f2bf(e0[r] * w0);
                    P1s[lo][4 * g + r] = f2bf(e1[r] * w1);
                }
            }
            SYNC();

            bf16x8 aP0 = *(const bf16x8*)&P0s[lo][g * 8];
            bf16x8 aP1 = *(const bf16x8*)&P1s[lo][g * 8];
#pragma unroll
            for (int n = 0; n < 4; ++n) {
                woC[n] = MFMA16(aP0, *(const bf16x8*)&VT[16 * n + lo][g * 8], woC[n]);
                wiC[n] = MFMA16(aP1, *(const bf16x8*)&KT[16 * n + lo][g * 8], wiC[n]);
            }
            if (g == 0) {
#pragma unroll
                for (int n = 0; n < 4; ++n)
#pragma unroll
                    for (int D = 0; D < 4; ++D) {
                        WiA[D][16 * n + lo] = f2bf(wiC[n][D]);
                        WoA[D][16 * n + lo] = f2bf(woC[n][D]);
                        if (it == 1) VT[16 * n + lo][16 + D] = f2bf(woC[n][D]);
                    }
            }
            SYNC();
        }
    }
}

// ---------------------------------------------------------------------------
// launch (R4-verified arrangement: fp32 ws pipeline, GATE in d_out,
// OBUF aliases Q)
// ---------------------------------------------------------------------------
extern "C" void kernel_launch(void* const* d_in, const int* in_sizes, int n_in,
                              void* d_out, int out_size, void* d_ws, size_t ws_size,
                              hipStream_t stream)
{
    const float* hs  = (const float*)d_in[0];
    const float* Wq  = (const float*)d_in[1];
    const float* Wk  = (const float*)d_in[2];
    const float* Wv  = (const float*)d_in[3];
    const float* Wlr = (const float*)d_in[4];
    const float* Wg  = (const float*)d_in[5];
    const float* Wo  = (const float*)d_in[6];
    const float* cq  = (const float*)d_in[7];
    const float* ck  = (const float*)d_in[8];
    const float* cv  = (const float*)d_in[9];
    const float* Wi0 = (const float*)d_in[10];
    const float* Wo0 = (const float*)d_in[11];
    const float* lng = (const float*)d_in[12];
    const float* lnb = (const float*)d_in[13];

    // ws (~203 MB): Q | K | V fp32 | LR | HALO. GATE lives in d_out.
    float* ws   = (float*)d_ws;
    float* Q    = ws;
    float* K    = Q + (size_t)NROWS * DIM;
    float* V    = K + (size_t)NROWS * DIM;
    float* LRb  = V + (size_t)NROWS * DIM;
    float* HALO = LRb + (size_t)NROWS * 32;
    float* GATE = (float*)d_out;
    float* OBUF = Q;   // alias: scan reads chunk's q before overwriting

    dim3 blk(256);

    gemm_nt_bf16<<<dim3(8, 128), blk, 0, stream>>>(hs, Wq, Q,    1024, DIM);
    gemm_nt_bf16<<<dim3(8, 128), blk, 0, stream>>>(hs, Wk, K,    1024, DIM);
    gemm_nt_bf16<<<dim3(8, 128), blk, 0, stream>>>(hs, Wv, V,    1024, DIM);
    gemm_nt_bf16<<<dim3(8, 128), blk, 0, stream>>>(hs, Wg, GATE, 1024, DIM);

    lr_kernel<<<NROWS, blk, 0, stream>>>(hs, Wlr, LRb);

    halo_save<<<3 * BATCH * (NSEG - 1) * 3, blk, 0, stream>>>(Q, K, V, HALO);
    conv_inplace<<<(3 * BATCH * NH * NSEG) / 4, blk, 0, stream>>>(Q, K, V, HALO,
                                                                  cq, ck, cv);

    scan_kernel<<<BATCH * NH, dim3(64), 0, stream>>>(Q, K, V, LRb, GATE,
                                                     Wi0, Wo0, lng, lnb, OBUF);

    gemm_nt_bf16<<<dim3(8, 128), blk, 0, stream>>>(OBUF, Wo, (float*)d_out,
                                                   1024, 1024);
}

// Round 10
// 2051.286 us; speedup vs baseline: 1.9905x; 1.0395x over previous
//
#include <hip/hip_runtime.h>
#include <cstdint>
#include <cstddef>

#define DIM    1024
#define NH     16
#define HD     64
#define CHUNK_ 16
#define SEQ    4096
#define BATCH  4
#define NROWS  (BATCH * SEQ)       // 16384
#define NCHUNK (SEQ / CHUNK_)      // 256
#define SEG    64
#define NSEG   (SEQ / SEG)         // 64

using bf16x8 = __attribute__((ext_vector_type(8))) short;
using f32x4  = __attribute__((ext_vector_type(4))) float;
typedef union { bf16x8 v; uint32_t u[4]; } B8;

#define MFMA16(a, b, c) __builtin_amdgcn_mfma_f32_16x16x32_bf16((a), (b), (c), 0, 0, 0)

__device__ __forceinline__ ushort f2bf(float f) {
    uint32_t u = __float_as_uint(f);
    u += 0x7FFFu + ((u >> 16) & 1u);      // RTNE
    return (ushort)(u >> 16);
}
__device__ __forceinline__ uint32_t pack2(float a, float b) {
    return (uint32_t)f2bf(a) | ((uint32_t)f2bf(b) << 16);
}
__device__ __forceinline__ float dot4(const float4 a, const float4 b) {
    return a.x*b.x + a.y*b.y + a.z*b.z + a.w*b.w;
}

// DPP row-of-16 rotate (VALU pipe, ~8cy vs ~30cy LDS-pipe shfl)
template <int N>
__device__ __forceinline__ float ror16(float x) {
    return __int_as_float(__builtin_amdgcn_update_dpp(
        0, __float_as_int(x), 0x120 + N, 0xF, 0xF, true));   // ROW_ROR:N
}
__device__ __forceinline__ float dppsum16(float x) {
    x += ror16<1>(x); x += ror16<2>(x);
    x += ror16<4>(x); x += ror16<8>(x);
    return x;
}

// single-wave "barrier": compiler-only fence (verified rounds 6-9)
#define SYNC() do { asm volatile("" ::: "memory");          \
                    __builtin_amdgcn_wave_barrier();        \
                    __builtin_amdgcn_sched_barrier(0); } while (0)

// ---------------------------------------------------------------------------
// bf16 MFMA GEMM (NT): fp32 in, inline RTNE pack, fp32 out (R4/R9-verified)
// ---------------------------------------------------------------------------
__global__ __launch_bounds__(256)
void gemm_nt_bf16(const float* __restrict__ A, const float* __restrict__ B,
                  float* __restrict__ C, int K, int ldc)
{
    __shared__ ushort As[128][64];
    __shared__ ushort Bs[128][64];

    const int tid  = threadIdx.x;
    const int m0   = blockIdx.y * 128, n0 = blockIdx.x * 128;
    const int wave = tid >> 6, lane = tid & 63;
    const int wm   = (wave >> 1) * 64, wn = (wave & 1) * 64;
    const int frow = lane & 15, fkg = lane >> 4;
    const int srow = tid >> 1, shalf = tid & 1;

    f32x4 acc[4][4];
#pragma unroll
    for (int i = 0; i < 4; ++i)
#pragma unroll
        for (int j = 0; j < 4; ++j) acc[i][j] = (f32x4){0.f, 0.f, 0.f, 0.f};

    const float* Ap0 = A + (size_t)(m0 + srow) * K + shalf * 16;
    const float* Bp0 = B + (size_t)(n0 + srow) * K + shalf * 16;
    const int swz0 = ((shalf * 2 + 0) ^ (srow & 7)) * 8;
    const int swz1 = ((shalf * 2 + 1) ^ (srow & 7)) * 8;
    const int rsw  = (frow & 7);

    for (int kt = 0; kt < K; kt += 32) {
        float4 a0 = *(const float4*)(Ap0 + kt);
        float4 a1 = *(const float4*)(Ap0 + kt + 4);
        float4 a2 = *(const float4*)(Ap0 + kt + 8);
        float4 a3 = *(const float4*)(Ap0 + kt + 12);
        float4 b0 = *(const float4*)(Bp0 + kt);
        float4 b1 = *(const float4*)(Bp0 + kt + 4);
        float4 b2 = *(const float4*)(Bp0 + kt + 8);
        float4 b3 = *(const float4*)(Bp0 + kt + 12);

        __syncthreads();
        uint4 u;
        u.x = pack2(a0.x, a0.y); u.y = pack2(a0.z, a0.w);
        u.z = pack2(a1.x, a1.y); u.w = pack2(a1.z, a1.w);
        *(uint4*)&As[srow][swz0] = u;
        u.x = pack2(a2.x, a2.y); u.y = pack2(a2.z, a2.w);
        u.z = pack2(a3.x, a3.y); u.w = pack2(a3.z, a3.w);
        *(uint4*)&As[srow][swz1] = u;
        u.x = pack2(b0.x, b0.y); u.y = pack2(b0.z, b0.w);
        u.z = pack2(b1.x, b1.y); u.w = pack2(b1.z, b1.w);
        *(uint4*)&Bs[srow][swz0] = u;
        u.x = pack2(b2.x, b2.y); u.y = pack2(b2.z, b2.w);
        u.z = pack2(b3.x, b3.y); u.w = pack2(b3.z, b3.w);
        *(uint4*)&Bs[srow][swz1] = u;
        __syncthreads();

        bf16x8 af[4], bf[4];
#pragma unroll
        for (int i = 0; i < 4; ++i) {
            af[i] = *(const bf16x8*)&As[wm + i * 16 + frow][(fkg ^ rsw) * 8];
            bf[i] = *(const bf16x8*)&Bs[wn + i * 16 + frow][(fkg ^ rsw) * 8];
        }
#pragma unroll
        for (int mt = 0; mt < 4; ++mt)
#pragma unroll
            for (int nt = 0; nt < 4; ++nt)
                acc[mt][nt] = MFMA16(af[mt], bf[nt], acc[mt][nt]);
    }

    const int col = lane & 15, r4 = (lane >> 4) * 4;
#pragma unroll
    for (int mt = 0; mt < 4; ++mt)
#pragma unroll
        for (int nt = 0; nt < 4; ++nt)
#pragma unroll
            for (int j = 0; j < 4; ++j)
                C[(size_t)(m0 + wm + mt * 16 + r4 + j) * ldc +
                  (n0 + wn + nt * 16 + col)] = acc[mt][nt][j];
}

// ---------------------------------------------------------------------------
// lr kernel (exact fp32)
// ---------------------------------------------------------------------------
__global__ __launch_bounds__(256)
void lr_kernel(const float* __restrict__ hs, const float* __restrict__ Wlr,
               float* __restrict__ LR)
{
    __shared__ float row[DIM];
    const int r = blockIdx.x;
    const int t = threadIdx.x;
    *(float4*)&row[t * 4] = *(const float4*)&hs[(size_t)r * DIM + t * 4];
    __syncthreads();

    const int o = t >> 3;
    const int p = t & 7;
    const float* w = Wlr + (size_t)o * DIM + p * 128;
    const float* x = row + p * 128;
    float acc = 0.f;
#pragma unroll
    for (int i = 0; i < 32; ++i) {
        float4 xv = *(const float4*)(x + i * 4);
        float4 wv = *(const float4*)(w + i * 4);
        acc += dot4(xv, wv);
    }
    acc += __shfl_xor(acc, 1);
    acc += __shfl_xor(acc, 2);
    acc += __shfl_xor(acc, 4);
    if (p == 0) {
        float xx = acc + 0.001f;
        LR[(size_t)r * 32 + o] = (xx > 20.f) ? xx : log1pf(expf(xx));
    }
}

// ---------------------------------------------------------------------------
// halo save (fp32)
// ---------------------------------------------------------------------------
__global__ __launch_bounds__(256)
void halo_save(const float* __restrict__ Q, const float* __restrict__ K,
               const float* __restrict__ V, float* __restrict__ HALO)
{
    int idx = blockIdx.x;
    int tn  = idx / (BATCH * (NSEG - 1) * 3);
    int rem = idx - tn * (BATCH * (NSEG - 1) * 3);
    int b   = rem / ((NSEG - 1) * 3);
    int rem2= rem - b * ((NSEG - 1) * 3);
    int s   = rem2 / 3 + 1;
    int j   = rem2 - (s - 1) * 3;

    const float* buf = (tn == 0) ? Q : ((tn == 1) ? K : V);
    size_t src = ((size_t)(b * SEQ + s * SEG - 3 + j)) * DIM + threadIdx.x * 4;
    size_t dst = ((size_t)((tn * BATCH + b) * NSEG + s) * 3 + j) * DIM + threadIdx.x * 4;
    *(float4*)&HALO[dst] = *(const float4*)&buf[src];
}

// ---------------------------------------------------------------------------
// conv in-place (fp32)
// ---------------------------------------------------------------------------
__global__ __launch_bounds__(256)
void conv_inplace(float* __restrict__ Q, float* __restrict__ K,
                  float* __restrict__ V, const float* __restrict__ HALO,
                  const float* __restrict__ cq, const float* __restrict__ ck,
                  const float* __restrict__ cv)
{
    const int wid  = (blockIdx.x << 2) + (threadIdx.x >> 6);
    const int lane = threadIdx.x & 63;
    const int tn   = wid >> 12;
    const int rem  = wid & 4095;
    const int b    = rem >> 10;
    const int rem2 = rem & 1023;
    const int h    = rem2 >> 6;
    const int s    = rem2 & 63;
    const int c    = (h << 6) + lane;

    float* buf = (tn == 0) ? Q : ((tn == 1) ? K : V);
    const float* cw = (tn == 0) ? cq : ((tn == 1) ? ck : cv);
    float4 w4 = *(const float4*)(cw + (c << 2));

    float xm3 = 0.f, xm2 = 0.f, xm1 = 0.f;
    if (s > 0) {
        size_t hb = ((size_t)((tn * BATCH + b) * NSEG + s) * 3) * DIM + c;
        xm3 = HALO[hb];
        xm2 = HALO[hb + DIM];
        xm1 = HALO[hb + 2 * DIM];
    }

    size_t base = ((size_t)(b * SEQ + s * SEG)) * DIM + c;
    float x_next = buf[base];
#pragma unroll 4
    for (int i = 0; i < SEG; ++i) {
        float x = x_next;
        if (i < SEG - 1) x_next = buf[base + (size_t)(i + 1) * DIM];
        float y = xm3 * w4.x + xm2 * w4.y + xm1 * w4.z + x * w4.w + x;
        y = y / (1.f + __expf(-y));
        if (tn < 2) {
            float n2 = y * y;
#pragma unroll
            for (int m = 1; m < 64; m <<= 1) n2 += __shfl_xor(n2, m);
            y *= rsqrtf(n2);
        }
        buf[base + (size_t)i * DIM] = y;
        xm3 = xm2; xm2 = xm1; xm1 = x;
    }
}

// ---------------------------------------------------------------------------
// MFMA scan, barrier-free, ONE WAVE per (b,h) chain, 64 blocks.
// R9-verified structure + this round: (1) DPP row_ror LN reductions,
// (2) P operands via register shuffle (scores+update merged, 5 SYNCs/chunk),
// (3) lr via prefetched direct loads (no bpermute).
// ---------------------------------------------------------------------------
__global__ __launch_bounds__(64)
void scan_kernel(const float* QP, const float* __restrict__ KP,
                 const float* __restrict__ VP, const float* __restrict__ LRb,
                 const float* __restrict__ GATE,
                 const float* __restrict__ Wi0, const float* __restrict__ Wo0,
                 const float* __restrict__ lng, const float* __restrict__ lnb,
                 float* OB)
{
    const int bh = blockIdx.x, b = bh >> 4, h = bh & 15;
    const int t  = threadIdx.x, lo = t & 15, g = t >> 4;

    __shared__ ushort KA[16][72], QA[16][72], VA[16][72];   // rows [l][d]
    __shared__ ushort KT[64][24];                           // K^T [d][l]
    __shared__ ushort VT[64][40];                           // [d][V^T | Wo^T | 0]
    __shared__ ushort WiA[16][72], WoA[16][72];             // [D][d], rows 4+ zero
    __shared__ ushort QKT[16][32];                          // [q][qk | q_h | 0]
    __shared__ ushort KH[16][32];
    __shared__ float  sG[16][68];

    for (int i = t; i < 16 * 72; i += 64) { ((ushort*)WiA)[i] = 0; ((ushort*)WoA)[i] = 0; }
    for (int i = t; i < 64 * 24; i += 64) ((ushort*)KT)[i] = 0;
    for (int i = t; i < 64 * 40; i += 64) ((ushort*)VT)[i] = 0;
    for (int i = t; i < 16 * 32; i += 64) { ((ushort*)QKT)[i] = 0; ((ushort*)KH)[i] = 0; }

    f32x4 wiC[4], woC[4];
#pragma unroll
    for (int n = 0; n < 4; ++n) { wiC[n] = (f32x4){0,0,0,0}; woC[n] = (f32x4){0,0,0,0}; }
    if (g == 0) {
#pragma unroll
        for (int n = 0; n < 4; ++n)
#pragma unroll
            for (int D = 0; D < 4; ++D) {
                float wi = Wi0[((size_t)D * NH + h) * HD + 16 * n + lo];
                float wo = Wo0[((size_t)D * NH + h) * HD + 16 * n + lo];
                wiC[n][D] = wi; woC[n][D] = wo;
                WiA[D][16 * n + lo] = f2bf(wi);
                WoA[D][16 * n + lo] = f2bf(wo);
                VT[16 * n + lo][16 + D] = f2bf(wo);
            }
    }
    SYNC();

    float lnGr[4], lnBr[4];
#pragma unroll
    for (int n = 0; n < 4; ++n) { lnGr[n] = lng[16 * n + lo]; lnBr[n] = lnb[16 * n + lo]; }

    const int rowb = b * SEQ;
    float4 pq[4], pk[4], pv[4], pg[4];
    float plr_q, plr_i, plr_o;
    {
#pragma unroll
        for (int i = 0; i < 4; ++i) {
            size_t go = (size_t)(rowb + i * 4 + g) * DIM + h * 64 + 4 * lo;
            pq[i] = *(const float4*)&QP[go];
            pk[i] = *(const float4*)&KP[go];
            pv[i] = *(const float4*)&VP[go];
            pg[i] = *(const float4*)&GATE[go];
        }
        plr_q = LRb[(size_t)(rowb + lo) * 32 + h * 2 + 1];
        plr_i = LRb[(size_t)rowb * 32 + h * 2];
        plr_o = LRb[(size_t)rowb * 32 + h * 2 + 1];
    }

    const f32x4 z4 = (f32x4){0.f, 0.f, 0.f, 0.f};
    const uint32_t pmsk = (g < 2) ? 0xFFFFFFFFu : 0u;   // zero k-slices 16..31
    const int L0 = (lo + 32 * g) & 63, L1 = (L0 + 16) & 63;

    for (int c = 0; c < NCHUNK; ++c) {
        const int rb = rowb + c * CHUNK_;

        // ---- phase 1: stage chunk (regs -> LDS, bf16 + transposed copies) ----
#pragma unroll
        for (int i = 0; i < 4; ++i) {
            const int row = i * 4 + g;
            *(float4*)&sG[row][4 * lo] = pg[i];
            uint2 uq; uq.x = pack2(pq[i].x, pq[i].y); uq.y = pack2(pq[i].z, pq[i].w);
            *(uint2*)&QA[row][4 * lo] = uq;
            uint2 uk; uk.x = pack2(pk[i].x, pk[i].y); uk.y = pack2(pk[i].z, pk[i].w);
            *(uint2*)&KA[row][4 * lo] = uk;
            uint2 uv; uv.x = pack2(pv[i].x, pv[i].y); uv.y = pack2(pv[i].z, pv[i].w);
            *(uint2*)&VA[row][4 * lo] = uv;
            KT[4 * lo + 0][row] = (ushort)(uk.x & 0xFFFF);
            KT[4 * lo + 1][row] = (ushort)(uk.x >> 16);
            KT[4 * lo + 2][row] = (ushort)(uk.y & 0xFFFF);
            KT[4 * lo + 3][row] = (ushort)(uk.y >> 16);
            VT[4 * lo + 0][row] = (ushort)(uv.x & 0xFFFF);
            VT[4 * lo + 1][row] = (ushort)(uv.x >> 16);
            VT[4 * lo + 2][row] = (ushort)(uv.y & 0xFFFF);
            VT[4 * lo + 3][row] = (ushort)(uv.y >> 16);
        }
        const float lr1    = plr_q;
        const float lr_in  = plr_i;
        const float lr_out = plr_o;

        // ---- prefetch next chunk ----
        if (c + 1 < NCHUNK) {
            const int rb2 = rb + CHUNK_;
#pragma unroll
            for (int i = 0; i < 4; ++i) {
                size_t go = (size_t)(rb2 + i * 4 + g) * DIM + h * 64 + 4 * lo;
                pq[i] = *(const float4*)&QP[go];
                pk[i] = *(const float4*)&KP[go];
                pv[i] = *(const float4*)&VP[go];
                pg[i] = *(const float4*)&GATE[go];
            }
            plr_q = LRb[(size_t)(rb2 + lo) * 32 + h * 2 + 1];
            plr_i = LRb[(size_t)rb2 * 32 + h * 2];
            plr_o = LRb[(size_t)rb2 * 32 + h * 2 + 1];
        }
        SYNC();

        // ---- phase 2: M1/M2 logits^T, softmaxD, M3 qk, bounce write ----
        bf16x8 xWi0 = *(const bf16x8*)&WiA[lo][g * 8];
        bf16x8 xWi1 = *(const bf16x8*)&WiA[lo][g * 8 + 32];
        f32x4 cK = MFMA16(xWi0, *(const bf16x8*)&KA[lo][g * 8], z4);
        cK = MFMA16(xWi1, *(const bf16x8*)&KA[lo][g * 8 + 32], cK);
        f32x4 cQ = MFMA16(xWi0, *(const bf16x8*)&QA[lo][g * 8], z4);
        cQ = MFMA16(xWi1, *(const bf16x8*)&QA[lo][g * 8 + 32], cQ);

        float mK = fmaxf(fmaxf(cK[0], cK[1]), fmaxf(cK[2], cK[3]));
        float ek0 = __expf(cK[0] - mK), ek1 = __expf(cK[1] - mK);
        float ek2 = __expf(cK[2] - mK), ek3 = __expf(cK[3] - mK);
        float ivk = lr1 / (ek0 + ek1 + ek2 + ek3);
        float kh0 = ek0 * ivk, kh1 = ek1 * ivk, kh2 = ek2 * ivk, kh3 = ek3 * ivk;

        float mQ = fmaxf(fmaxf(cQ[0], cQ[1]), fmaxf(cQ[2], cQ[3]));
        float eq0 = __expf(cQ[0] - mQ), eq1 = __expf(cQ[1] - mQ);
        float eq2 = __expf(cQ[2] - mQ), eq3 = __expf(cQ[3] - mQ);
        float ivq = 1.f / (eq0 + eq1 + eq2 + eq3);
        float qh0 = eq0 * ivq, qh1 = eq1 * ivq, qh2 = eq2 * ivq, qh3 = eq3 * ivq;

        B8 aQh, bKh;
        aQh.u[0] = aQh.u[1] = aQh.u[2] = aQh.u[3] = 0;
        bKh.u[0] = bKh.u[1] = bKh.u[2] = bKh.u[3] = 0;
        if (g == 0) {
            aQh.u[0] = pack2(qh0, qh1); aQh.u[1] = pack2(qh2, qh3);
            bKh.u[0] = pack2(kh0, kh1); bKh.u[1] = pack2(kh2, kh3);
        }
        f32x4 cQK = MFMA16(aQh.v, bKh.v, z4);

#pragma unroll
        for (int r = 0; r < 4; ++r) {
            const int q = 4 * g + r;
            QKT[q][lo] = (lo <= q) ? f2bf(cQK[r]) : (ushort)0;
        }
        if (g == 0) {
            QKT[lo][16] = f2bf(qh0); QKT[lo][17] = f2bf(qh1);
            QKT[lo][18] = f2bf(qh2); QKT[lo][19] = f2bf(qh3);
            KH[0][lo] = f2bf(kh0); KH[1][lo] = f2bf(kh1);
            KH[2][lo] = f2bf(kh2); KH[3][lo] = f2bf(kh3);
        }
        SYNC();

        // ---- phase 3: M4 o, LN (DPP) + gate + store, update1 ----
        bf16x8 aO = *(const bf16x8*)&QKT[lo][g * 8];
        f32x4 oA[4];
#pragma unroll
        for (int n = 0; n < 4; ++n)
            oA[n] = MFMA16(aO, *(const bf16x8*)&VT[16 * n + lo][g * 8], z4);
#pragma unroll
        for (int r = 0; r < 4; ++r) {
            float s1 = oA[0][r] + oA[1][r] + oA[2][r] + oA[3][r];
            float s2 = oA[0][r] * oA[0][r] + oA[1][r] * oA[1][r] +
                       oA[2][r] * oA[2][r] + oA[3][r] * oA[3][r];
            s1 = dppsum16(s1); s2 = dppsum16(s2);
            float mu = s1 * (1.f / 64.f);
            float rstd = rsqrtf(s2 * (1.f / 64.f) - mu * mu + 1e-5f);
            const int q = 4 * g + r;
#pragma unroll
            for (int n = 0; n < 4; ++n) {
                float val = (oA[n][r] - mu) * rstd * lnGr[n] + lnBr[n];
                val *= sG[q][16 * n + lo];
                OB[(size_t)(rb + q) * DIM + h * 64 + 16 * n + lo] = val;
            }
        }
        {
            bf16x8 aKH = *(const bf16x8*)&KH[lo][g * 8];
#pragma unroll
            for (int n = 0; n < 4; ++n)
                woC[n] = MFMA16(aKH, *(const bf16x8*)&VT[16 * n + lo][g * 8], woC[n]);
        }
        if (g == 0) {
#pragma unroll
            for (int n = 0; n < 4; ++n)
#pragma unroll
                for (int D = 0; D < 4; ++D)
                    WoA[D][16 * n + lo] = f2bf(woC[n][D]);
        }
        SYNC();

        // ---- phases 4,5: inner TTT (scores + update fused, P via shfl) ----
#pragma unroll
        for (int it = 0; it < 2; ++it) {
            bf16x8 aK0 = *(const bf16x8*)&KA[lo][g * 8];
            bf16x8 aK1 = *(const bf16x8*)&KA[lo][g * 8 + 32];
            bf16x8 aV0 = *(const bf16x8*)&VA[lo][g * 8];
            bf16x8 aV1 = *(const bf16x8*)&VA[lo][g * 8 + 32];
            bf16x8 bWi0 = *(const bf16x8*)&WiA[lo][g * 8];
            bf16x8 bWi1 = *(const bf16x8*)&WiA[lo][g * 8 + 32];
            bf16x8 bWo0 = *(const bf16x8*)&WoA[lo][g * 8];
            bf16x8 bWo1 = *(const bf16x8*)&WoA[lo][g * 8 + 32];
            f32x4 s0T = MFMA16(aK0, bWi0, z4);
            s0T = MFMA16(aK1, bWi1, s0T);
            f32x4 s1T = MFMA16(aV0, bWo0, z4);
            s1T = MFMA16(aV1, bWo1, s1T);

            // softmax over j (j = 4g+r): regs + 2 cross-row shfls
            float x0[4], x1[4];
#pragma unroll
            for (int r = 0; r < 4; ++r) {
                x0[r] = s0T[r] * 0.125f;
                x1[r] = s1T[r] * 0.125f;
            }
            float m0 = fmaxf(fmaxf(x0[0], x0[1]), fmaxf(x0[2], x0[3]));
            float m1 = fmaxf(fmaxf(x1[0], x1[1]), fmaxf(x1[2], x1[3]));
            m0 = fmaxf(m0, __shfl_xor(m0, 16)); m0 = fmaxf(m0, __shfl_xor(m0, 32));
            m1 = fmaxf(m1, __shfl_xor(m1, 16)); m1 = fmaxf(m1, __shfl_xor(m1, 32));
            float e0[4], e1[4];
#pragma unroll
            for (int r = 0; r < 4; ++r) {
                e0[r] = __expf(x0[r] - m0);
                e1[r] = __expf(x1[r] - m1);
            }
            float su0 = e0[0] + e0[1] + e0[2] + e0[3];
            float su1 = e1[0] + e1[1] + e1[2] + e1[3];
            su0 += __shfl_xor(su0, 16); su0 += __shfl_xor(su0, 32);
            su1 += __shfl_xor(su1, 16); su1 += __shfl_xor(su1, 32);
            const float w0 = lr_out / su0;
            const float w1 = lr_in / su1;

            // pack p[j=4g+r][D=lo] and shuffle into X-frag layout:
            // lane (lo,g) needs p[D=lo][j=8g..8g+7] <- lanes lo+32g, lo+32g+16
            uint32_t p00 = pack2(e0[0] * w0, e0[1] * w0);
            uint32_t p01 = pack2(e0[2] * w0, e0[3] * w0);
            uint32_t p10 = pack2(e1[0] * w1, e1[1] * w1);
            uint32_t p11 = pack2(e1[2] * w1, e1[3] * w1);
            B8 aP0, aP1;
            aP0.u[0] = (uint32_t)__shfl((int)p00, L0) & pmsk;
            aP0.u[1] = (uint32_t)__shfl((int)p01, L0) & pmsk;
            aP0.u[2] = (uint32_t)__shfl((int)p00, L1) & pmsk;
            aP0.u[3] = (uint32_t)__shfl((int)p01, L1) & pmsk;
            aP1.u[0] = (uint32_t)__shfl((int)p10, L0) & pmsk;
            aP1.u[1] = (uint32_t)__shfl((int)p11, L0) & pmsk;
            aP1.u[2] = (uint32_t)__shfl((int)p10, L1) & pmsk;
            aP1.u[3] = (uint32_t)__shfl((int)p11, L1) & pmsk;

#pragma unroll
            for (int n = 0; n < 4; ++n) {
                woC[n] = MFMA16(aP0.v, *(const bf16x8*)&VT[16 * n + lo][g * 8], woC[n]);
                wiC[n] = MFMA16(aP1.v, *(const bf16x8*)&KT[16 * n + lo][g * 8], wiC[n]);
            }
            if (g == 0) {
#pragma unroll
                for (int n = 0; n < 4; ++n)
#pragma unroll
                    for (int D = 0; D < 4; ++D) {
                        WiA[D][16 * n + lo] = f2bf(wiC[n][D]);
                        WoA[D][16 * n + lo] = f2bf(woC[n][D]);
                        if (it == 1) VT[16 * n + lo][16 + D] = f2bf(woC[n][D]);
                    }
            }
            SYNC();
        }
    }
}

// ---------------------------------------------------------------------------
// launch (R4/R9-verified arrangement)
// ---------------------------------------------------------------------------
extern "C" void kernel_launch(void* const* d_in, const int* in_sizes, int n_in,
                              void* d_out, int out_size, void* d_ws, size_t ws_size,
                              hipStream_t stream)
{
    const float* hs  = (const float*)d_in[0];
    const float* Wq  = (const float*)d_in[1];
    const float* Wk  = (const float*)d_in[2];
    const float* Wv  = (const float*)d_in[3];
    const float* Wlr = (const float*)d_in[4];
    const float* Wg  = (const float*)d_in[5];
    const float* Wo  = (const float*)d_in[6];
    const float* cq  = (const float*)d_in[7];
    const float* ck  = (const float*)d_in[8];
    const float* cv  = (const float*)d_in[9];
    const float* Wi0 = (const float*)d_in[10];
    const float* Wo0 = (const float*)d_in[11];
    const float* lng = (const float*)d_in[12];
    const float* lnb = (const float*)d_in[13];

    // ws (~203 MB): Q | K | V fp32 | LR | HALO. GATE lives in d_out.
    float* ws   = (float*)d_ws;
    float* Q    = ws;
    float* K    = Q + (size_t)NROWS * DIM;
    float* V    = K + (size_t)NROWS * DIM;
    float* LRb  = V + (size_t)NROWS * DIM;
    float* HALO = LRb + (size_t)NROWS * 32;
    float* GATE = (float*)d_out;
    float* OBUF = Q;   // alias: scan reads chunk's q before overwriting

    dim3 blk(256);

    gemm_nt_bf16<<<dim3(8, 128), blk, 0, stream>>>(hs, Wq, Q,    1024, DIM);
    gemm_nt_bf16<<<dim3(8, 128), blk, 0, stream>>>(hs, Wk, K,    1024, DIM);
    gemm_nt_bf16<<<dim3(8, 128), blk, 0, stream>>>(hs, Wv, V,    1024, DIM);
    gemm_nt_bf16<<<dim3(8, 128), blk, 0, stream>>>(hs, Wg, GATE, 1024, DIM);

    lr_kernel<<<NROWS, blk, 0, stream>>>(hs, Wlr, LRb);

    halo_save<<<3 * BATCH * (NSEG - 1) * 3, blk, 0, stream>>>(Q, K, V, HALO);
    conv_inplace<<<(3 * BATCH * NH * NSEG) / 4, blk, 0, stream>>>(Q, K, V, HALO,
                                                                  cq, ck, cv);

    scan_kernel<<<BATCH * NH, dim3(64), 0, stream>>>(Q, K, V, LRb, GATE,
                                                     Wi0, Wo0, lng, lnb, OBUF);

    gemm_nt_bf16<<<dim3(8, 128), blk, 0, stream>>>(OBUF, Wo, (float*)d_out,
                                                   1024, 1024);
}

// Round 11
// 1750.815 us; speedup vs baseline: 2.3322x; 1.1716x over previous
//
#include <hip/hip_runtime.h>
#include <cstdint>
#include <cstddef>

#define DIM    1024
#define NH     16
#define HD     64
#define CHUNK_ 16
#define SEQ    4096
#define BATCH  4
#define NROWS  (BATCH * SEQ)       // 16384
#define NCHUNK (SEQ / CHUNK_)      // 256
#define SEG    64
#define NSEG   (SEQ / SEG)         // 64

using bf16x8 = __attribute__((ext_vector_type(8))) short;
using f32x4  = __attribute__((ext_vector_type(4))) float;
typedef union { bf16x8 v; uint32_t u[4]; } B8;

#define MFMA16(a, b, c) __builtin_amdgcn_mfma_f32_16x16x32_bf16((a), (b), (c), 0, 0, 0)

__device__ __forceinline__ ushort f2bf(float f) {
    uint32_t u = __float_as_uint(f);
    u += 0x7FFFu + ((u >> 16) & 1u);      // RTNE
    return (ushort)(u >> 16);
}
__device__ __forceinline__ uint32_t pack2(float a, float b) {
    return (uint32_t)f2bf(a) | ((uint32_t)f2bf(b) << 16);
}
__device__ __forceinline__ float b2f(ushort u) {
    return __uint_as_float(((uint32_t)u) << 16);
}
__device__ __forceinline__ float dot4(const float4 a, const float4 b) {
    return a.x*b.x + a.y*b.y + a.z*b.z + a.w*b.w;
}

// DPP row-of-16 rotate reduction (VALU pipe) — verified R10
template <int N>
__device__ __forceinline__ float ror16(float x) {
    return __int_as_float(__builtin_amdgcn_update_dpp(
        0, __float_as_int(x), 0x120 + N, 0xF, 0xF, true));   // ROW_ROR:N
}
__device__ __forceinline__ float dppsum16(float x) {
    x += ror16<1>(x); x += ror16<2>(x);
    x += ror16<4>(x); x += ror16<8>(x);
    return x;
}

// single-wave "barrier": compiler-only fence (verified rounds 6-10)
#define SYNC() do { asm volatile("" ::: "memory");          \
                    __builtin_amdgcn_wave_barrier();        \
                    __builtin_amdgcn_sched_barrier(0); } while (0)

__device__ __forceinline__ void gl_lds16(const void* g, void* l) {
    __builtin_amdgcn_global_load_lds(
        (const __attribute__((address_space(1))) void*)g,
        (__attribute__((address_space(3))) void*)l, 16, 0, 0);
}

// ---------------------------------------------------------------------------
// fp32 -> bf16 converter (verified R6-R8)
// ---------------------------------------------------------------------------
__global__ __launch_bounds__(256)
void f2b_kernel(const float* __restrict__ in, ushort* __restrict__ out, int n8)
{
    int i = blockIdx.x * 256 + threadIdx.x;
    const int stride = gridDim.x * 256;
    for (; i < n8; i += stride) {
        float4 a = *(const float4*)&in[(size_t)i * 8];
        float4 b = *(const float4*)&in[(size_t)i * 8 + 4];
        uint4 u;
        u.x = pack2(a.x, a.y); u.y = pack2(a.z, a.w);
        u.z = pack2(b.x, b.y); u.w = pack2(b.z, b.w);
        *(uint4*)&out[(size_t)i * 8] = u;
    }
}

// ---------------------------------------------------------------------------
// m97-style bf16 GEMM (NT): global_load_lds staging (linear LDS dest,
// inverse-swizzled global source, swizzled frag read — rule 21).
// BK=64, 128x128 tile, 4 waves. Two output variants.
// ---------------------------------------------------------------------------
#define GEMM_LDS_BODY(EPILOG)                                                  \
    __shared__ ushort As[128][64];                                             \
    __shared__ ushort Bs[128][64];                                             \
    const int tid  = threadIdx.x, wave = tid >> 6, lane = tid & 63;            \
    const int m0   = blockIdx.y * 128, n0 = blockIdx.x * 128;                  \
    const int lo   = lane & 15, kg = lane >> 4;                                \
    const int wm   = (wave >> 1) * 64, wn = (wave & 1) * 64;                   \
    const int rin  = lane >> 3, sl = lane & 7;                                 \
    const int sb   = 32 * wave;                                                \
    f32x4 acc[4][4];                                                           \
    _Pragma("unroll")                                                          \
    for (int i = 0; i < 4; ++i)                                                \
        _Pragma("unroll")                                                      \
        for (int j = 0; j < 4; ++j) acc[i][j] = (f32x4){0.f, 0.f, 0.f, 0.f};   \
    const int swz = lo & 7;                                                    \
    for (int kt = 0; kt < K; kt += 64) {                                       \
        __syncthreads();                                                       \
        _Pragma("unroll")                                                      \
        for (int i = 0; i < 4; ++i) {                                          \
            const int row = sb + 8 * i + rin;                                  \
            const int gs  = sl ^ (row & 7);                                    \
            gl_lds16(A + (size_t)(m0 + row) * K + kt + gs * 8,                 \
                     &As[sb + 8 * i][0]);                                      \
            gl_lds16(B + (size_t)(n0 + row) * K + kt + gs * 8,                 \
                     &Bs[sb + 8 * i][0]);                                      \
        }                                                                      \
        __syncthreads();                                                       \
        bf16x8 af[2][4], bfr[2][4];                                            \
        _Pragma("unroll")                                                      \
        for (int kk = 0; kk < 2; ++kk)                                         \
            _Pragma("unroll")                                                  \
            for (int m = 0; m < 4; ++m) {                                      \
                const int s = (kk * 4 + kg) ^ swz;                             \
                af[kk][m]  = *(const bf16x8*)&As[wm + m * 16 + lo][s * 8];     \
                bfr[kk][m] = *(const bf16x8*)&Bs[wn + m * 16 + lo][s * 8];     \
            }                                                                  \
        _Pragma("unroll")                                                      \
        for (int kk = 0; kk < 2; ++kk)                                         \
            _Pragma("unroll")                                                  \
            for (int mt = 0; mt < 4; ++mt)                                     \
                _Pragma("unroll")                                              \
                for (int nt = 0; nt < 4; ++nt)                                 \
                    acc[mt][nt] = MFMA16(af[kk][mt], bfr[kk][nt], acc[mt][nt]);\
    }                                                                          \
    const int col = lane & 15, r4 = (lane >> 4) * 4;                           \
    _Pragma("unroll")                                                          \
    for (int mt = 0; mt < 4; ++mt)                                             \
        _Pragma("unroll")                                                      \
        for (int nt = 0; nt < 4; ++nt)                                         \
            _Pragma("unroll")                                                  \
            for (int j = 0; j < 4; ++j) {                                      \
                size_t idx = (size_t)(m0 + wm + mt * 16 + r4 + j) * DIM +      \
                             n0 + wn + nt * 16 + col;                          \
                EPILOG;                                                        \
            }

__global__ __launch_bounds__(256)
void gemm_lds_b16o(const ushort* __restrict__ A, const ushort* __restrict__ B,
                   ushort* __restrict__ C, int K)
{
    GEMM_LDS_BODY(C[idx] = f2bf(acc[mt][nt][j]))
}

__global__ __launch_bounds__(256)
void gemm_lds_f32o(const ushort* __restrict__ A, const ushort* __restrict__ B,
                   float* __restrict__ C, int K)
{
    GEMM_LDS_BODY(C[idx] = acc[mt][nt][j])
}

// ---------------------------------------------------------------------------
// lr kernel (exact fp32)
// ---------------------------------------------------------------------------
__global__ __launch_bounds__(256)
void lr_kernel(const float* __restrict__ hs, const float* __restrict__ Wlr,
               float* __restrict__ LR)
{
    __shared__ float row[DIM];
    const int r = blockIdx.x;
    const int t = threadIdx.x;
    *(float4*)&row[t * 4] = *(const float4*)&hs[(size_t)r * DIM + t * 4];
    __syncthreads();

    const int o = t >> 3;
    const int p = t & 7;
    const float* w = Wlr + (size_t)o * DIM + p * 128;
    const float* x = row + p * 128;
    float acc = 0.f;
#pragma unroll
    for (int i = 0; i < 32; ++i) {
        float4 xv = *(const float4*)(x + i * 4);
        float4 wv = *(const float4*)(w + i * 4);
        acc += dot4(xv, wv);
    }
    acc += __shfl_xor(acc, 1);
    acc += __shfl_xor(acc, 2);
    acc += __shfl_xor(acc, 4);
    if (p == 0) {
        float xx = acc + 0.001f;
        LR[(size_t)r * 32 + o] = (xx > 20.f) ? xx : log1pf(expf(xx));
    }
}

// ---------------------------------------------------------------------------
// halo save (bf16 — verified R7/R8)
// ---------------------------------------------------------------------------
__global__ __launch_bounds__(256)
void halo_save(const ushort* __restrict__ Q, const ushort* __restrict__ K,
               const ushort* __restrict__ V, ushort* __restrict__ HALO)
{
    int idx = blockIdx.x;
    int tn  = idx / (BATCH * (NSEG - 1) * 3);
    int rem = idx - tn * (BATCH * (NSEG - 1) * 3);
    int b   = rem / ((NSEG - 1) * 3);
    int rem2= rem - b * ((NSEG - 1) * 3);
    int s   = rem2 / 3 + 1;
    int j   = rem2 - (s - 1) * 3;

    const ushort* buf = (tn == 0) ? Q : ((tn == 1) ? K : V);
    size_t src = ((size_t)(b * SEQ + s * SEG - 3 + j)) * DIM + threadIdx.x * 4;
    size_t dst = ((size_t)((tn * BATCH + b) * NSEG + s) * 3 + j) * DIM + threadIdx.x * 4;
    *(uint2*)&HALO[dst] = *(const uint2*)&buf[src];
}

// ---------------------------------------------------------------------------
// conv in-place (bf16 buffers, fp32 math — verified R7/R8)
// ---------------------------------------------------------------------------
__global__ __launch_bounds__(256)
void conv_inplace(ushort* __restrict__ Q, ushort* __restrict__ K,
                  ushort* __restrict__ V, const ushort* __restrict__ HALO,
                  const float* __restrict__ cq, const float* __restrict__ ck,
                  const float* __restrict__ cv)
{
    const int wid  = (blockIdx.x << 2) + (threadIdx.x >> 6);
    const int lane = threadIdx.x & 63;
    const int tn   = wid >> 12;
    const int rem  = wid & 4095;
    const int b    = rem >> 10;
    const int rem2 = rem & 1023;
    const int h    = rem2 >> 6;
    const int s    = rem2 & 63;
    const int c    = (h << 6) + lane;

    ushort* buf = (tn == 0) ? Q : ((tn == 1) ? K : V);
    const float* cw = (tn == 0) ? cq : ((tn == 1) ? ck : cv);
    float4 w4 = *(const float4*)(cw + (c << 2));

    float xm3 = 0.f, xm2 = 0.f, xm1 = 0.f;
    if (s > 0) {
        size_t hb = ((size_t)((tn * BATCH + b) * NSEG + s) * 3) * DIM + c;
        xm3 = b2f(HALO[hb]);
        xm2 = b2f(HALO[hb + DIM]);
        xm1 = b2f(HALO[hb + 2 * DIM]);
    }

    size_t base = ((size_t)(b * SEQ + s * SEG)) * DIM + c;
    float x_next = b2f(buf[base]);
#pragma unroll 4
    for (int i = 0; i < SEG; ++i) {
        float x = x_next;
        if (i < SEG - 1) x_next = b2f(buf[base + (size_t)(i + 1) * DIM]);
        float y = xm3 * w4.x + xm2 * w4.y + xm1 * w4.z + x * w4.w + x;
        y = y / (1.f + __expf(-y));
        if (tn < 2) {
            float n2 = y * y;
#pragma unroll
            for (int m = 1; m < 64; m <<= 1) n2 += __shfl_xor(n2, m);
            y *= rsqrtf(n2);
        }
        buf[base + (size_t)i * DIM] = f2bf(y);
        xm3 = xm2; xm2 = xm1; xm1 = x;
    }
}

// ---------------------------------------------------------------------------
// MFMA scan, barrier-free, ONE WAVE per (b,h) chain, 64 blocks.
// R10-verified math. This round: bf16 Q/K/V inputs (uint2 prefetch, no
// pack2 in stage); DOUBLE-BUFFERED chunk tiles — chunk c+1 staged at the
// END of chunk c (loads issued at chunk top -> latency fully hidden);
// SYNCs 5 -> 4 per chunk. bf16 output.
// ---------------------------------------------------------------------------
__global__ __launch_bounds__(64)
void scan_kernel(const ushort* QP, const ushort* __restrict__ KP,
                 const ushort* __restrict__ VP, const float* __restrict__ LRb,
                 const float* __restrict__ GATE,
                 const float* __restrict__ Wi0, const float* __restrict__ Wo0,
                 const float* __restrict__ lng, const float* __restrict__ lnb,
                 ushort* OB)
{
    const int bh = blockIdx.x, b = bh >> 4, h = bh & 15;
    const int t  = threadIdx.x, lo = t & 15, g = t >> 4;

    __shared__ ushort KA2[2][16][72], QA2[2][16][72], VA2[2][16][72];
    __shared__ float  sG2[2][16][68];
    __shared__ ushort KT2[2][64][24];
    __shared__ ushort VT2[2][64][40];            // [d][V^T | Wo^T(16-19) | 0]
    __shared__ ushort WiA[16][72], WoA[16][72];  // rows 4-15 zero
    __shared__ ushort QKT[16][32], KH[16][32];

    for (int i = t; i < 16 * 72; i += 64) { ((ushort*)WiA)[i] = 0; ((ushort*)WoA)[i] = 0; }
    for (int i = t; i < 2 * 64 * 24; i += 64) ((ushort*)KT2)[i] = 0;
    for (int i = t; i < 2 * 64 * 40; i += 64) ((ushort*)VT2)[i] = 0;
    for (int i = t; i < 16 * 32; i += 64) { ((ushort*)QKT)[i] = 0; ((ushort*)KH)[i] = 0; }

    f32x4 wiC[4], woC[4];
#pragma unroll
    for (int n = 0; n < 4; ++n) { wiC[n] = (f32x4){0,0,0,0}; woC[n] = (f32x4){0,0,0,0}; }
    if (g == 0) {
#pragma unroll
        for (int n = 0; n < 4; ++n)
#pragma unroll
            for (int D = 0; D < 4; ++D) {
                float wi = Wi0[((size_t)D * NH + h) * HD + 16 * n + lo];
                float wo = Wo0[((size_t)D * NH + h) * HD + 16 * n + lo];
                wiC[n][D] = wi; woC[n][D] = wo;
                WiA[D][16 * n + lo] = f2bf(wi);
                WoA[D][16 * n + lo] = f2bf(wo);
                VT2[0][16 * n + lo][16 + D] = f2bf(wo);
            }
    }
    SYNC();

    float lnGr[4], lnBr[4];
#pragma unroll
    for (int n = 0; n < 4; ++n) { lnGr[n] = lng[16 * n + lo]; lnBr[n] = lnb[16 * n + lo]; }

    const int rowb = b * SEQ;
    const ushort* QPh = QP + h * 64;
    const ushort* KPh = KP + h * 64;
    const ushort* VPh = VP + h * 64;
    const float*  GPh = GATE + h * 64;
    ushort*       OBh = OB + h * 64;

    uint2 pq[4], pk[4], pv[4];
    float4 pg[4];
    float plr_q, plr_i, plr_o;

    // prefetch chunk 0
    {
#pragma unroll
        for (int i = 0; i < 4; ++i) {
            size_t go = (size_t)(rowb + i * 4 + g) * DIM + 4 * lo;
            pq[i] = *(const uint2*)&QPh[go];
            pk[i] = *(const uint2*)&KPh[go];
            pv[i] = *(const uint2*)&VPh[go];
            pg[i] = *(const float4*)&GPh[go];
        }
        plr_q = LRb[(size_t)(rowb + lo) * 32 + h * 2 + 1];
        plr_i = LRb[(size_t)rowb * 32 + h * 2];
        plr_o = LRb[(size_t)rowb * 32 + h * 2 + 1];
    }

    auto STAGE = [&](int nb) {
#pragma unroll
        for (int i = 0; i < 4; ++i) {
            const int row = i * 4 + g;
            *(float4*)&sG2[nb][row][4 * lo] = pg[i];
            *(uint2*)&QA2[nb][row][4 * lo] = pq[i];
            *(uint2*)&KA2[nb][row][4 * lo] = pk[i];
            *(uint2*)&VA2[nb][row][4 * lo] = pv[i];
            uint2 uk = pk[i], uv = pv[i];
            KT2[nb][4 * lo + 0][row] = (ushort)(uk.x & 0xFFFF);
            KT2[nb][4 * lo + 1][row] = (ushort)(uk.x >> 16);
            KT2[nb][4 * lo + 2][row] = (ushort)(uk.y & 0xFFFF);
            KT2[nb][4 * lo + 3][row] = (ushort)(uk.y >> 16);
            VT2[nb][4 * lo + 0][row] = (ushort)(uv.x & 0xFFFF);
            VT2[nb][4 * lo + 1][row] = (ushort)(uv.x >> 16);
            VT2[nb][4 * lo + 2][row] = (ushort)(uv.y & 0xFFFF);
            VT2[nb][4 * lo + 3][row] = (ushort)(uv.y >> 16);
        }
    };

    STAGE(0);
    SYNC();

    const f32x4 z4 = (f32x4){0.f, 0.f, 0.f, 0.f};
    const uint32_t pmsk = (g < 2) ? 0xFFFFFFFFu : 0u;   // zero k-slices 16..31
    const int L0 = (lo + 32 * g) & 63, L1 = (L0 + 16) & 63;

    for (int c = 0; c < NCHUNK; ++c) {
        const int rb  = rowb + c * CHUNK_;
        const int cur = c & 1, nxt = cur ^ 1;
        ushort (*KAc)[72] = KA2[cur];
        ushort (*QAc)[72] = QA2[cur];
        ushort (*VAc)[72] = VA2[cur];
        float  (*sGc)[68] = sG2[cur];
        ushort (*KTc)[24] = KT2[cur];
        ushort (*VTc)[40] = VT2[cur];

        const float lr1    = plr_q;
        const float lr_in  = plr_i;
        const float lr_out = plr_o;

        // ---- issue prefetch for chunk c+1 (lands during this chunk) ----
        if (c + 1 < NCHUNK) {
            const int rb2 = rb + CHUNK_;
#pragma unroll
            for (int i = 0; i < 4; ++i) {
                size_t go = (size_t)(rb2 + i * 4 + g) * DIM + 4 * lo;
                pq[i] = *(const uint2*)&QPh[go];
                pk[i] = *(const uint2*)&KPh[go];
                pv[i] = *(const uint2*)&VPh[go];
                pg[i] = *(const float4*)&GPh[go];
            }
            plr_q = LRb[(size_t)(rb2 + lo) * 32 + h * 2 + 1];
            plr_i = LRb[(size_t)rb2 * 32 + h * 2];
            plr_o = LRb[(size_t)rb2 * 32 + h * 2 + 1];
        }

        // ---- phase A: M1/M2 logits^T, softmaxD, M3 qk, bounce write ----
        bf16x8 xWi0 = *(const bf16x8*)&WiA[lo][g * 8];
        bf16x8 xWi1 = *(const bf16x8*)&WiA[lo][g * 8 + 32];
        f32x4 cK = MFMA16(xWi0, *(const bf16x8*)&KAc[lo][g * 8], z4);
        cK = MFMA16(xWi1, *(const bf16x8*)&KAc[lo][g * 8 + 32], cK);
        f32x4 cQ = MFMA16(xWi0, *(const bf16x8*)&QAc[lo][g * 8], z4);
        cQ = MFMA16(xWi1, *(const bf16x8*)&QAc[lo][g * 8 + 32], cQ);

        float mK = fmaxf(fmaxf(cK[0], cK[1]), fmaxf(cK[2], cK[3]));
        float ek0 = __expf(cK[0] - mK), ek1 = __expf(cK[1] - mK);
        float ek2 = __expf(cK[2] - mK), ek3 = __expf(cK[3] - mK);
        float ivk = lr1 / (ek0 + ek1 + ek2 + ek3);
        float kh0 = ek0 * ivk, kh1 = ek1 * ivk, kh2 = ek2 * ivk, kh3 = ek3 * ivk;

        float mQ = fmaxf(fmaxf(cQ[0], cQ[1]), fmaxf(cQ[2], cQ[3]));
        float eq0 = __expf(cQ[0] - mQ), eq1 = __expf(cQ[1] - mQ);
        float eq2 = __expf(cQ[2] - mQ), eq3 = __expf(cQ[3] - mQ);
        float ivq = 1.f / (eq0 + eq1 + eq2 + eq3);
        float qh0 = eq0 * ivq, qh1 = eq1 * ivq, qh2 = eq2 * ivq, qh3 = eq3 * ivq;

        B8 aQh, bKh;
        aQh.u[0] = aQh.u[1] = aQh.u[2] = aQh.u[3] = 0;
        bKh.u[0] = bKh.u[1] = bKh.u[2] = bKh.u[3] = 0;
        if (g == 0) {
            aQh.u[0] = pack2(qh0, qh1); aQh.u[1] = pack2(qh2, qh3);
            bKh.u[0] = pack2(kh0, kh1); bKh.u[1] = pack2(kh2, kh3);
        }
        f32x4 cQK = MFMA16(aQh.v, bKh.v, z4);

#pragma unroll
        for (int r = 0; r < 4; ++r) {
            const int q = 4 * g + r;
            QKT[q][lo] = (lo <= q) ? f2bf(cQK[r]) : (ushort)0;
        }
        if (g == 0) {
            QKT[lo][16] = f2bf(qh0); QKT[lo][17] = f2bf(qh1);
            QKT[lo][18] = f2bf(qh2); QKT[lo][19] = f2bf(qh3);
            KH[0][lo] = f2bf(kh0); KH[1][lo] = f2bf(kh1);
            KH[2][lo] = f2bf(kh2); KH[3][lo] = f2bf(kh3);
        }
        SYNC();

        // ---- phase B: M4 o, LN (DPP) + gate + bf16 store, update1 ----
        bf16x8 aO = *(const bf16x8*)&QKT[lo][g * 8];
        f32x4 oA[4];
#pragma unroll
        for (int n = 0; n < 4; ++n)
            oA[n] = MFMA16(aO, *(const bf16x8*)&VTc[16 * n + lo][g * 8], z4);
#pragma unroll
        for (int r = 0; r < 4; ++r) {
            float s1 = oA[0][r] + oA[1][r] + oA[2][r] + oA[3][r];
            float s2 = oA[0][r] * oA[0][r] + oA[1][r] * oA[1][r] +
                       oA[2][r] * oA[2][r] + oA[3][r] * oA[3][r];
            s1 = dppsum16(s1); s2 = dppsum16(s2);
            float mu = s1 * (1.f / 64.f);
            float rstd = rsqrtf(s2 * (1.f / 64.f) - mu * mu + 1e-5f);
            const int q = 4 * g + r;
#pragma unroll
            for (int n = 0; n < 4; ++n) {
                float val = (oA[n][r] - mu) * rstd * lnGr[n] + lnBr[n];
                val *= sGc[q][16 * n + lo];
                OBh[(size_t)(rb + q) * DIM + 16 * n + lo] = f2bf(val);
            }
        }
        {
            bf16x8 aKH = *(const bf16x8*)&KH[lo][g * 8];
#pragma unroll
            for (int n = 0; n < 4; ++n)
                woC[n] = MFMA16(aKH, *(const bf16x8*)&VTc[16 * n + lo][g * 8], woC[n]);
        }
        if (g == 0) {
#pragma unroll
            for (int n = 0; n < 4; ++n)
#pragma unroll
                for (int D = 0; D < 4; ++D)
                    WoA[D][16 * n + lo] = f2bf(woC[n][D]);
        }
        SYNC();

        // ---- phases C,D: inner TTT (transposed scores, P via shfl) ----
#pragma unroll
        for (int it = 0; it < 2; ++it) {
            bf16x8 aK0 = *(const bf16x8*)&KAc[lo][g * 8];
            bf16x8 aK1 = *(const bf16x8*)&KAc[lo][g * 8 + 32];
            bf16x8 aV0 = *(const bf16x8*)&VAc[lo][g * 8];
            bf16x8 aV1 = *(const bf16x8*)&VAc[lo][g * 8 + 32];
            bf16x8 bWi0 = *(const bf16x8*)&WiA[lo][g * 8];
            bf16x8 bWi1 = *(const bf16x8*)&WiA[lo][g * 8 + 32];
            bf16x8 bWo0 = *(const bf16x8*)&WoA[lo][g * 8];
            bf16x8 bWo1 = *(const bf16x8*)&WoA[lo][g * 8 + 32];
            f32x4 s0T = MFMA16(aK0, bWi0, z4);
            s0T = MFMA16(aK1, bWi1, s0T);
            f32x4 s1T = MFMA16(aV0, bWo0, z4);
            s1T = MFMA16(aV1, bWo1, s1T);

            float x0[4], x1[4];
#pragma unroll
            for (int r = 0; r < 4; ++r) {
                x0[r] = s0T[r] * 0.125f;
                x1[r] = s1T[r] * 0.125f;
            }
            float m0 = fmaxf(fmaxf(x0[0], x0[1]), fmaxf(x0[2], x0[3]));
            float m1 = fmaxf(fmaxf(x1[0], x1[1]), fmaxf(x1[2], x1[3]));
            m0 = fmaxf(m0, __shfl_xor(m0, 16)); m0 = fmaxf(m0, __shfl_xor(m0, 32));
            m1 = fmaxf(m1, __shfl_xor(m1, 16)); m1 = fmaxf(m1, __shfl_xor(m1, 32));
            float e0[4], e1[4];
#pragma unroll
            for (int r = 0; r < 4; ++r) {
                e0[r] = __expf(x0[r] - m0);
                e1[r] = __expf(x1[r] - m1);
            }
            float su0 = e0[0] + e0[1] + e0[2] + e0[3];
            float su1 = e1[0] + e1[1] + e1[2] + e1[3];
            su0 += __shfl_xor(su0, 16); su0 += __shfl_xor(su0, 32);
            su1 += __shfl_xor(su1, 16); su1 += __shfl_xor(su1, 32);
            const float w0 = lr_out / su0;
            const float w1 = lr_in / su1;

            uint32_t p00 = pack2(e0[0] * w0, e0[1] * w0);
            uint32_t p01 = pack2(e0[2] * w0, e0[3] * w0);
            uint32_t p10 = pack2(e1[0] * w1, e1[1] * w1);
            uint32_t p11 = pack2(e1[2] * w1, e1[3] * w1);
            B8 aP0, aP1;
            aP0.u[0] = (uint32_t)__shfl((int)p00, L0) & pmsk;
            aP0.u[1] = (uint32_t)__shfl((int)p01, L0) & pmsk;
            aP0.u[2] = (uint32_t)__shfl((int)p00, L1) & pmsk;
            aP0.u[3] = (uint32_t)__shfl((int)p01, L1) & pmsk;
            aP1.u[0] = (uint32_t)__shfl((int)p10, L0) & pmsk;
            aP1.u[1] = (uint32_t)__shfl((int)p11, L0) & pmsk;
            aP1.u[2] = (uint32_t)__shfl((int)p10, L1) & pmsk;
            aP1.u[3] = (uint32_t)__shfl((int)p11, L1) & pmsk;

#pragma unroll
            for (int n = 0; n < 4; ++n) {
                woC[n] = MFMA16(aP0.v, *(const bf16x8*)&VTc[16 * n + lo][g * 8], woC[n]);
                wiC[n] = MFMA16(aP1.v, *(const bf16x8*)&KTc[16 * n + lo][g * 8], wiC[n]);
            }

            // stage next chunk's tiles into the other buffer (it==1 only;
            // overlaps the g==0 write-back tail; loads issued ~9K cy ago)
            if (it == 1 && c + 1 < NCHUNK) STAGE(nxt);

            if (g == 0) {
#pragma unroll
                for (int n = 0; n < 4; ++n)
#pragma unroll
                    for (int D = 0; D < 4; ++D) {
                        WiA[D][16 * n + lo] = f2bf(wiC[n][D]);
                        WoA[D][16 * n + lo] = f2bf(woC[n][D]);
                        if (it == 1) VT2[nxt][16 * n + lo][16 + D] = f2bf(woC[n][D]);
                    }
            }
            SYNC();
        }
    }
}

// ---------------------------------------------------------------------------
// launch — all-bf16 dataflow, ws ≈ 151 MB (safely under the proven 213 MB)
// ---------------------------------------------------------------------------
extern "C" void kernel_launch(void* const* d_in, const int* in_sizes, int n_in,
                              void* d_out, int out_size, void* d_ws, size_t ws_size,
                              hipStream_t stream)
{
    const float* hs  = (const float*)d_in[0];
    const float* Wq  = (const float*)d_in[1];
    const float* Wk  = (const float*)d_in[2];
    const float* Wv  = (const float*)d_in[3];
    const float* Wlr = (const float*)d_in[4];
    const float* Wg  = (const float*)d_in[5];
    const float* Wo  = (const float*)d_in[6];
    const float* cq  = (const float*)d_in[7];
    const float* ck  = (const float*)d_in[8];
    const float* cv  = (const float*)d_in[9];
    const float* Wi0 = (const float*)d_in[10];
    const float* Wo0 = (const float*)d_in[11];
    const float* lng = (const float*)d_in[12];
    const float* lnb = (const float*)d_in[13];

    ushort* Qb   = (ushort*)d_ws;
    ushort* Kb   = Qb + (size_t)NROWS * DIM;
    ushort* Vb   = Kb + (size_t)NROWS * DIM;
    ushort* hsb  = Vb + (size_t)NROWS * DIM;
    ushort* Wqb  = hsb + (size_t)NROWS * DIM;
    ushort* Wkb  = Wqb + (size_t)DIM * DIM;
    ushort* Wvb  = Wkb + (size_t)DIM * DIM;
    ushort* Wgb  = Wvb + (size_t)DIM * DIM;
    ushort* Wob  = Wgb + (size_t)DIM * DIM;
    ushort* HALO = Wob + (size_t)DIM * DIM;
    float*  LRb  = (float*)(HALO + (size_t)3 * BATCH * NSEG * 3 * DIM);
    float*  GATE = (float*)d_out;
    ushort* OBUF = hsb;   // hs bf16 dead after projections (stream-ordered)

    dim3 blk(256);

    f2b_kernel<<<2048, blk, 0, stream>>>(hs, hsb, NROWS * DIM / 8);
    f2b_kernel<<<512, blk, 0, stream>>>(Wq, Wqb, DIM * DIM / 8);
    f2b_kernel<<<512, blk, 0, stream>>>(Wk, Wkb, DIM * DIM / 8);
    f2b_kernel<<<512, blk, 0, stream>>>(Wv, Wvb, DIM * DIM / 8);
    f2b_kernel<<<512, blk, 0, stream>>>(Wg, Wgb, DIM * DIM / 8);
    f2b_kernel<<<512, blk, 0, stream>>>(Wo, Wob, DIM * DIM / 8);

    gemm_lds_b16o<<<dim3(8, 128), blk, 0, stream>>>(hsb, Wqb, Qb, 1024);
    gemm_lds_b16o<<<dim3(8, 128), blk, 0, stream>>>(hsb, Wkb, Kb, 1024);
    gemm_lds_b16o<<<dim3(8, 128), blk, 0, stream>>>(hsb, Wvb, Vb, 1024);
    gemm_lds_f32o<<<dim3(8, 128), blk, 0, stream>>>(hsb, Wgb, GATE, 1024);

    lr_kernel<<<NROWS, blk, 0, stream>>>(hs, Wlr, LRb);

    halo_save<<<3 * BATCH * (NSEG - 1) * 3, blk, 0, stream>>>(Qb, Kb, Vb, HALO);
    conv_inplace<<<(3 * BATCH * NH * NSEG) / 4, blk, 0, stream>>>(Qb, Kb, Vb, HALO,
                                                                  cq, ck, cv);

    scan_kernel<<<BATCH * NH, dim3(64), 0, stream>>>(Qb, Kb, Vb, LRb, GATE,
                                                     Wi0, Wo0, lng, lnb, OBUF);

    gemm_lds_f32o<<<dim3(8, 128), blk, 0, stream>>>(OBUF, Wob, (float*)d_out, 1024);
}